// Round 4
// baseline (59523.895 us; speedup 1.0000x reference)
//
#include <hip/hip_runtime.h>

// ============================================================================
// R4: fence-free coherence — all cross-WG data via relaxed agent-scope atomics
// (sc1 write-through / L2-bypass reads); monotonic phase-numbered 2-level
// barrier (no resets, no release, no wbl2/inv); 3 barriers/step schedule:
// A:{ATT(t),OUT(t-1)} B:{L2(t),L1(t+1)} C:{L3(t)}. 107 WGs.
// Label: "R4 fence-free sc1, 3-phase, monotonic barrier"
// ============================================================================

#define DI __device__ __forceinline__

typedef _Float16 f16;
typedef _Float16 f16x8 __attribute__((ext_vector_type(8)));
typedef _Float16 f16x4 __attribute__((ext_vector_type(4)));
typedef float f32x4 __attribute__((ext_vector_type(4)));
typedef unsigned long long u64;

constexpr int Tn = 800, Un = 96, Hn = 400;
// K-layouts (f16, zero-padded to 32-multiples):
//  A1/W1: [w 64 | h1 400 | x 3 | 0..] P1=520, ks 0..15
//  A2/W2: [w 64 | h1 400 | x 3 | 0(13) | h2rec 400 | 0..] P2=904, ks 0..27
//  A3/W3: [w 64 | h2 400 | x 3 | 0(13) | h3rec 400 | 0..] P3=904, ks 0..27
//  AM/WM: [h1 400 | h2 400 | h3 400 | 0(88)] PM=1288, ks 0..39; AM x3 slots
constexpr int P1 = 520, P2 = 904, P3 = 904, PM = 1288, KPWM = 10;
constexpr int NWG = 107, NGRP = 8;

constexpr size_t OFF_W1 = 0;
constexpr size_t SZ_W1 = (size_t)1600 * P1 * 2;
constexpr size_t OFF_W2 = OFF_W1 + SZ_W1;
constexpr size_t SZ_W2 = (size_t)1600 * P2 * 2;
constexpr size_t OFF_W3 = OFF_W2 + SZ_W2;
constexpr size_t OFF_WM = OFF_W3 + SZ_W2;
constexpr size_t SZ_WM = (size_t)128 * PM * 2;
constexpr size_t OFF_A1 = OFF_WM + SZ_WM;
constexpr size_t SZ_A1 = (size_t)2 * 64 * P1 * 2;
constexpr size_t OFF_A2 = OFF_A1 + SZ_A1;
constexpr size_t SZ_A2 = (size_t)2 * 64 * P2 * 2;
constexpr size_t OFF_A3 = OFF_A2 + SZ_A2;
constexpr size_t OFF_AM = OFF_A3 + SZ_A2;
constexpr size_t SZ_AM = (size_t)3 * 64 * PM * 2;   // triple-buffered
constexpr size_t OFF_TEB = OFF_AM + SZ_AM;
constexpr size_t SZ_TEB = (size_t)64 * 96 * 64 * 2;
constexpr size_t OFF_BS1 = OFF_TEB + SZ_TEB;
constexpr size_t OFF_BS2 = OFF_BS1 + 6400;
constexpr size_t OFF_BS3 = OFF_BS2 + 6400;
constexpr size_t OFF_BW = OFF_BS3 + 6400;
constexpr size_t OFF_BM = OFF_BW + 128;
constexpr size_t OFF_BAR = OFF_BM + 512;
constexpr size_t SZ_BAR = 8192;
constexpr size_t OFF_RES = OFF_BAR + SZ_BAR;

// output offsets (fp32 elements): eos,pi,mux,muy,sx,sy,rho
constexpr size_t O_EOS = 0, O_PI = 51200, O_MUX = 1075200, O_MUY = 2099200;
constexpr size_t O_SX = 3123200, O_SY = 4147200, O_RHO = 5171200;

// ---- relaxed agent-scope (sc1) data movers: no fences needed anywhere ----
DI f16x8 ldA16(const f16* p) {
  u64 lo = __hip_atomic_load((u64*)p, __ATOMIC_RELAXED, __HIP_MEMORY_SCOPE_AGENT);
  u64 hi = __hip_atomic_load((u64*)(p + 4), __ATOMIC_RELAXED, __HIP_MEMORY_SCOPE_AGENT);
  union { u64 u[2]; f16x8 v; } c;
  c.u[0] = lo; c.u[1] = hi;
  return c.v;
}
DI u64 ldU8(const f16* p) {
  return __hip_atomic_load((u64*)p, __ATOMIC_RELAXED, __HIP_MEMORY_SCOPE_AGENT);
}
DI void stA4(f16* p, f16x4 v) {
  union { f16x4 v; u64 u; } c; c.v = v;
  __hip_atomic_store((u64*)p, c.u, __ATOMIC_RELAXED, __HIP_MEMORY_SCOPE_AGENT);
}
DI void stU8(f16* p, u64 u) {
  __hip_atomic_store((u64*)p, u, __ATOMIC_RELAXED, __HIP_MEMORY_SCOPE_AGENT);
}

// ---- monotonic phase-numbered 2-level grid barrier (all relaxed) ----
// Ordering: __syncthreads drains each wave's sc1 stores (vmcnt(0)) before
// thread0's arrival add; consumers' sc1 loads bypass L1/L2 after the poll.
DI void gridbar(unsigned* barr, unsigned ph) {
  __syncthreads();
  if (threadIdx.x == 0) {
    const int id = (int)blockIdx.x;
    const int g = id & (NGRP - 1);
    unsigned* cnt = barr + g * 32;
    unsigned* root = barr + NGRP * 32;
    __hip_atomic_fetch_add(cnt, 1u, __ATOMIC_RELAXED, __HIP_MEMORY_SCOPE_AGENT);
    if (id < NGRP) {  // block g (g<8) leads group g
      const unsigned gsz = (unsigned)((g < (NWG % NGRP)) ? (NWG / NGRP + 1) : (NWG / NGRP));
      const unsigned tgt = ph * gsz;
      int guard = 0;
      while (__hip_atomic_load(cnt, __ATOMIC_RELAXED, __HIP_MEMORY_SCOPE_AGENT) < tgt) {
        __builtin_amdgcn_s_sleep(1);
        if (++guard > 50000000) break;  // failsafe vs hang
      }
      __hip_atomic_fetch_add(root, 1u, __ATOMIC_RELAXED, __HIP_MEMORY_SCOPE_AGENT);
    }
    const unsigned rtgt = ph * (unsigned)NGRP;
    int guard = 0;
    while (__hip_atomic_load(root, __ATOMIC_RELAXED, __HIP_MEMORY_SCOPE_AGENT) < rtgt) {
      __builtin_amdgcn_s_sleep(1);
      if (++guard > 50000000) break;
    }
  }
  __syncthreads();
}

DI float sigm(float v) { return 1.f / (1.f + expf(-v)); }

// ---- shared LSTM slot: wave-per-gate, m=64, j-tile=16; dC may be nullptr ----
template <int KS, int PITCH>
DI void lstm_slot(const f16x8* wr, const f16* Ain, char* smem, int tid,
                  const float* bL, float* cst,
                  f16* dA, int pA, f16* dB, int pB, f16* dC, int pC) {
  const int wave = tid >> 6, lane = tid & 63, ln16 = lane & 15, quad = lane >> 4;
  float* red = (float*)smem;  // [gate 4][b 64][j 16]
  f32x4 acc[4];
#pragma unroll
  for (int mt = 0; mt < 4; ++mt) acc[mt] = f32x4{0.f, 0.f, 0.f, 0.f};
#pragma unroll
  for (int i = 0; i < KS; ++i) {
    const int kc = i * 32 + quad * 8;
#pragma unroll
    for (int mt = 0; mt < 4; ++mt) {
      const f16x8 a = ldA16(Ain + (mt * 16 + ln16) * PITCH + kc);
      acc[mt] = __builtin_amdgcn_mfma_f32_16x16x32_f16(a, wr[i], acc[mt], 0, 0, 0);
    }
  }
#pragma unroll
  for (int mt = 0; mt < 4; ++mt)
#pragma unroll
    for (int r = 0; r < 4; ++r)
      red[wave * 1024 + (mt * 16 + quad * 4 + r) * 16 + ln16] = acc[mt][r];
  __syncthreads();
  {
    const int oi = tid * 4, b = oi >> 4, j0 = oi & 15;
    f32x4 gi = *(f32x4*)&red[oi];
    f32x4 gf = *(f32x4*)&red[1024 + oi];
    f32x4 gg = *(f32x4*)&red[2048 + oi];
    f32x4 go = *(f32x4*)&red[3072 + oi];
    f32x4 c = *(f32x4*)&cst[oi];
    f16x4 hv;
#pragma unroll
    for (int e = 0; e < 4; ++e) {
      const float iv = sigm(gi[e] + bL[j0 + e]);
      const float fv = sigm(gf[e] + bL[16 + j0 + e]);
      const float gv = tanhf(gg[e] + bL[32 + j0 + e]);
      const float ov = sigm(go[e] + bL[48 + j0 + e]);
      const float cn = fv * c[e] + iv * gv;
      c[e] = cn;
      hv[e] = (f16)(ov * tanhf(cn));
    }
    *(f32x4*)&cst[oi] = c;
    stA4(dA + b * pA + j0, hv);
    stA4(dB + b * pB + j0, hv);
    if (dC != nullptr) stA4(dC + b * pC + j0, hv);
  }
  __syncthreads();
}

// ---- LSTM1 role (25 WGs, ids 0..24): phase B computes L1(t+1); L1(0) pre-loop
DI void l1_role(char* ws, char* smem, int jb) {
  const int tid = threadIdx.x;
  const int wave = tid >> 6, lane = tid & 63, ln16 = lane & 15, quad = lane >> 4;
  const f16* W1 = (const f16*)(ws + OFF_W1);
  f16* A1 = (f16*)(ws + OFF_A1);
  f16* A2 = (f16*)(ws + OFF_A2);
  f16* AM = (f16*)(ws + OFF_AM);
  unsigned* barr = (unsigned*)(ws + OFF_BAR);
  float* cst = (float*)(smem + 16384);
  float* bL = (float*)(smem + 20480);
  const int row = wave * Hn + jb * 16 + ln16;
  f16x8 wr[16];
#pragma unroll
  for (int i = 0; i < 16; ++i) wr[i] = *(const f16x8*)(W1 + (size_t)row * P1 + i * 32 + quad * 8);
  if (tid < 64) bL[tid] = ((const float*)(ws + OFF_BS1))[(tid >> 4) * Hn + jb * 16 + (tid & 15)];
  for (int z = tid; z < 1024; z += 256) cst[z] = 0.f;
  __syncthreads();
  auto step = [&](int s) {
    lstm_slot<16, P1>(wr, A1 + (size_t)(s & 1) * 64 * P1, smem, tid, bL, cst,
                      A1 + (size_t)((s + 1) & 1) * 64 * P1 + 64 + jb * 16, P1,
                      A2 + (size_t)(s & 1) * 64 * P2 + 64 + jb * 16, P2,
                      AM + (size_t)(s % 3) * 64 * PM + jb * 16, PM);
  };
  unsigned ph = 0;
  step(0);
  gridbar(barr, ++ph);
  for (int t = 0; t < Tn; ++t) {
    gridbar(barr, ++ph);                 // end phase A
    if (t < Tn - 1) step(t + 1);         // phase B
    gridbar(barr, ++ph);                 // end phase B
    gridbar(barr, ++ph);                 // end phase C
  }
}

// ---- LSTM2 role (25 WGs): phase B computes L2(t)
DI void l2_role(char* ws, char* smem, int jb) {
  const int tid = threadIdx.x;
  const int wave = tid >> 6, lane = tid & 63, ln16 = lane & 15, quad = lane >> 4;
  const f16* W2 = (const f16*)(ws + OFF_W2);
  f16* A2 = (f16*)(ws + OFF_A2);
  f16* A3 = (f16*)(ws + OFF_A3);
  f16* AM = (f16*)(ws + OFF_AM);
  unsigned* barr = (unsigned*)(ws + OFF_BAR);
  float* cst = (float*)(smem + 16384);
  float* bL = (float*)(smem + 20480);
  const int row = wave * Hn + jb * 16 + ln16;
  f16x8 wr[28];
#pragma unroll
  for (int i = 0; i < 28; ++i) wr[i] = *(const f16x8*)(W2 + (size_t)row * P2 + i * 32 + quad * 8);
  if (tid < 64) bL[tid] = ((const float*)(ws + OFF_BS2))[(tid >> 4) * Hn + jb * 16 + (tid & 15)];
  for (int z = tid; z < 1024; z += 256) cst[z] = 0.f;
  __syncthreads();
  unsigned ph = 0;
  gridbar(barr, ++ph);
  for (int t = 0; t < Tn; ++t) {
    gridbar(barr, ++ph);                 // end phase A
    lstm_slot<28, P2>(wr, A2 + (size_t)(t & 1) * 64 * P2, smem, tid, bL, cst,
                      A2 + (size_t)((t + 1) & 1) * 64 * P2 + 480 + jb * 16, P2,
                      A3 + (size_t)(t & 1) * 64 * P3 + 64 + jb * 16, P3,
                      AM + (size_t)(t % 3) * 64 * PM + Hn + jb * 16, PM);
    gridbar(barr, ++ph);                 // end phase B
    gridbar(barr, ++ph);                 // end phase C
  }
}

// ---- LSTM3 role (25 WGs): phase C computes L3(t)
DI void l3_role(char* ws, char* smem, int jb) {
  const int tid = threadIdx.x;
  const int wave = tid >> 6, lane = tid & 63, ln16 = lane & 15, quad = lane >> 4;
  const f16* W3 = (const f16*)(ws + OFF_W3);
  f16* A3 = (f16*)(ws + OFF_A3);
  f16* AM = (f16*)(ws + OFF_AM);
  unsigned* barr = (unsigned*)(ws + OFF_BAR);
  float* cst = (float*)(smem + 16384);
  float* bL = (float*)(smem + 20480);
  const int row = wave * Hn + jb * 16 + ln16;
  f16x8 wr[28];
#pragma unroll
  for (int i = 0; i < 28; ++i) wr[i] = *(const f16x8*)(W3 + (size_t)row * P3 + i * 32 + quad * 8);
  if (tid < 64) bL[tid] = ((const float*)(ws + OFF_BS3))[(tid >> 4) * Hn + jb * 16 + (tid & 15)];
  for (int z = tid; z < 1024; z += 256) cst[z] = 0.f;
  __syncthreads();
  unsigned ph = 0;
  gridbar(barr, ++ph);
  for (int t = 0; t < Tn; ++t) {
    gridbar(barr, ++ph);                 // end phase A
    gridbar(barr, ++ph);                 // end phase B
    lstm_slot<28, P3>(wr, A3 + (size_t)(t & 1) * 64 * P3, smem, tid, bL, cst,
                      A3 + (size_t)((t + 1) & 1) * 64 * P3 + 480 + jb * 16, P3,
                      AM + (size_t)(t % 3) * 64 * PM + 2 * Hn + jb * 16, PM,
                      nullptr, 0);
    gridbar(barr, ++ph);                 // end phase C
  }
}

// ---- attention role (16 WGs x 4 batches): phase A computes ATT(t)
DI void att_role(char* ws, char* smem, int ab, const float* x, const float* Ww) {
  const int tid = threadIdx.x;
  const int b0 = ab * 4;
  f16* A1 = (f16*)(ws + OFF_A1);
  f16* A2 = (f16*)(ws + OFF_A2);
  f16* A3 = (f16*)(ws + OFF_A3);
  unsigned* barr = (unsigned*)(ws + OFF_BAR);
  f16* tebL = (f16*)smem;                 // 4*96*64 f16 = 49152
  f16* h1L = (f16*)(smem + 49152);        // 4*400 f16 = 3200
  float* ps = (float*)(smem + 52352);     // 960 f32
  float* pL = (float*)(smem + 56192);     // 120
  float* aL = (float*)(smem + 56672);     // 40
  float* beL = (float*)(smem + 56832);    // 40
  float* kaL = (float*)(smem + 56992);    // 40 (persistent kappa)
  float* phiL = (float*)(smem + 57152);   // 384
  float* bwL = (float*)(smem + 58688);    // 30
  f16* wL = (f16*)(smem + 58816);         // 256 f16 = 512B
  const int pr = tid >> 3, psd = tid & 7;
  float wwr[50];
  if (tid < 240) {
#pragma unroll
    for (int k = 0; k < 50; ++k) wwr[k] = Ww[pr * 400 + psd * 50 + k];
  }
  for (int i = tid; i < 24576; i += 256)
    tebL[i] = ((const f16*)(ws + OFF_TEB))[(size_t)b0 * 6144 + i];
  if (tid < 40) kaL[tid] = 0.f;
  if (tid < 30) bwL[tid] = ((const float*)(ws + OFF_BW))[tid];
  __syncthreads();

  unsigned ph = 0;
  gridbar(barr, ++ph);
  for (int t = 0; t < Tn; ++t) {
    // ---- phase A: attention step t ----
    {
      const f16* h1p = A2 + (size_t)(t & 1) * 64 * P2;
      for (int i = tid; i < 400; i += 256) {   // 4 batches x 100 u64 chunks of h1
        const int b = i / 100, c = i % 100;
        ((u64*)h1L)[i] = ldU8(h1p + (b0 + b) * P2 + 64 + c * 4);
      }
      __syncthreads();
      if (tid < 240) {
#pragma unroll 1
        for (int b = 0; b < 4; ++b) {
          const f16* hh = &h1L[b * 400 + psd * 50];
          float a = 0.f;
#pragma unroll
          for (int k = 0; k < 50; ++k) a += wwr[k] * (float)hh[k];
          ps[(b * 30 + pr) * 8 + psd] = a;
        }
      }
      __syncthreads();
      if (tid < 120) {
        const int b = tid / 30, r = tid % 30;
        float v = bwL[r];
#pragma unroll
        for (int s = 0; s < 8; ++s) v += ps[(b * 30 + r) * 8 + s];
        pL[b * 30 + r] = v;
      }
      __syncthreads();
      if (tid < 40) {
        const int b = tid / 10, k = tid % 10;
        aL[tid] = expf(pL[b * 30 + k]);
        beL[tid] = expf(pL[b * 30 + 10 + k]);
        kaL[tid] += expf(fminf(5.f, fmaxf(-10.f, pL[b * 30 + 20 + k])));
      }
      __syncthreads();
      for (int idx = tid; idx < 384; idx += 256) {
        const int b = idx / 96;
        const float u1 = (float)(idx % 96 + 1);
        float s = 0.f;
#pragma unroll
        for (int k = 0; k < 10; ++k) {
          const float d = kaL[b * 10 + k] - u1;
          s += aL[b * 10 + k] * expf(-beL[b * 10 + k] * d * d);
        }
        phiL[idx] = s;
      }
      __syncthreads();
      {
        const int b = tid >> 6, d = tid & 63;
        float wv = 0.f;
        for (int u = 0; u < 96; ++u) wv += phiL[b * 96 + u] * (float)tebL[(b * 96 + u) * 64 + d];
        wL[tid] = (f16)wv;
      }
      __syncthreads();
      if (tid < 64) {  // 8B-chunk atomic stores of w(t)
        const u64 wq = ((u64*)wL)[tid];
        const int bg = b0 + (tid >> 4), d0 = (tid & 15) * 4;
        stU8(A1 + (size_t)((t + 1) & 1) * 64 * P1 + bg * P1 + d0, wq);  // L1(t+1)
        stU8(A2 + (size_t)(t & 1) * 64 * P2 + bg * P2 + d0, wq);        // L2(t)
        stU8(A3 + (size_t)(t & 1) * 64 * P3 + bg * P3 + d0, wq);        // L3(t)
      }
      if (t + 1 < Tn && tid < 4) {  // stage x(t+1) as one 8B chunk [x0,x1,x2,0]
        const int b = b0 + tid;
        const float* xp = x + ((size_t)b * Tn + (t + 1)) * 3;
        f16x4 xv = {(f16)xp[0], (f16)xp[1], (f16)xp[2], (f16)0.f};
        stA4(A1 + (size_t)((t + 1) & 1) * 64 * P1 + b * P1 + 464, xv);
        stA4(A2 + (size_t)((t + 1) & 1) * 64 * P2 + b * P2 + 464, xv);
        stA4(A3 + (size_t)((t + 1) & 1) * 64 * P3 + b * P3 + 464, xv);
      }
    }
    gridbar(barr, ++ph);                 // end phase A
    gridbar(barr, ++ph);                 // end phase B
    gridbar(barr, ++ph);                 // end phase C
  }
}

// ---- output projection role (16 WGs): phase A computes OUT(t-1); tail OUT(Tn-1)
DI void out_role(char* ws, char* smem, int sub) {
  const int tid = threadIdx.x;
  const int wave = tid >> 6, lane = tid & 63, ln16 = lane & 15, quad = lane >> 4;
  const int mh = sub >> 3, nt = sub & 7;
  const int m0 = mh * 32;
  const f16* WM = (const f16*)(ws + OFF_WM);
  const f16* AM = (const f16*)(ws + OFF_AM);
  float* resb = (float*)(ws + OFF_RES);
  unsigned* barr = (unsigned*)(ws + OFF_BAR);
  float* red = (float*)smem;             // 8KB
  float* bmL = (float*)(smem + 8192);    // 16
  f16x8 wm[KPWM];
#pragma unroll
  for (int i = 0; i < KPWM; ++i) {
    const int ks = wave * KPWM + i;
    wm[i] = *(const f16x8*)(WM + (size_t)(nt * 16 + ln16) * PM + ks * 32 + quad * 8);
  }
  if (tid < 16) bmL[tid] = ((const float*)(ws + OFF_BM))[nt * 16 + tid];
  __syncthreads();

  auto step = [&](int s) {
    const f16* Ap = AM + (size_t)(s % 3) * 64 * PM;
    f32x4 acc[2];
    acc[0] = f32x4{0.f, 0.f, 0.f, 0.f};
    acc[1] = f32x4{0.f, 0.f, 0.f, 0.f};
#pragma unroll
    for (int i = 0; i < KPWM; ++i) {
      const int kc = (wave * KPWM + i) * 32 + quad * 8;
      const f16x8 a0 = ldA16(Ap + (m0 + ln16) * PM + kc);
      const f16x8 a1 = ldA16(Ap + (m0 + 16 + ln16) * PM + kc);
      acc[0] = __builtin_amdgcn_mfma_f32_16x16x32_f16(a0, wm[i], acc[0], 0, 0, 0);
      acc[1] = __builtin_amdgcn_mfma_f32_16x16x32_f16(a1, wm[i], acc[1], 0, 0, 0);
    }
#pragma unroll
    for (int mt = 0; mt < 2; ++mt)
      *(f32x4*)&red[((wave * 2 + mt) << 8) + (ln16 << 4) + (quad << 2)] = acc[mt];
    __syncthreads();
#pragma unroll
    for (int e = 0; e < 2; ++e) {
      const int oi = tid * 2 + e;
      const int m = oi & 31, cc = oi >> 5;
      const int mt = m >> 4, mr = m & 15;
      float v = bmL[cc];
#pragma unroll
      for (int wv = 0; wv < 4; ++wv) v += red[((wv * 2 + mt) << 8) + (cc << 4) + mr];
      resb[((size_t)s * 64 + m0 + m) * 128 + nt * 16 + cc] = v;
    }
    __syncthreads();
  };

  unsigned ph = 0;
  gridbar(barr, ++ph);
  for (int t = 0; t < Tn; ++t) {
    if (t >= 1) step(t - 1);             // phase A
    gridbar(barr, ++ph);                 // end phase A
    gridbar(barr, ++ph);                 // end phase B
    gridbar(barr, ++ph);                 // end phase C
  }
  step(Tn - 1);                          // tail: AM(Tn-1) complete since C(Tn-1)
}

__global__ void __launch_bounds__(256, 1) coop_kernel(char* ws, const float* x, const float* Ww) {
  __shared__ char smem[59392];
  const int id = (int)blockIdx.x;
  if (id < 25) l1_role(ws, smem, id);
  else if (id < 50) l2_role(ws, smem, id - 25);
  else if (id < 75) l3_role(ws, smem, id - 50);
  else if (id < 91) att_role(ws, smem, id - 75, x, Ww);
  else out_role(ws, smem, id - 91);
}

// ---- init: build f16 weight layouts, zero A-buffers, gather text emb ----
__global__ void init_build(char* ws, const int* tok, const float* emb,
                           const float* Wih1, const float* Whh1, const float* bih1, const float* bhh1,
                           const float* Wih2, const float* Whh2, const float* bih2, const float* bhh2,
                           const float* Wih3, const float* Whh3, const float* bih3, const float* bhh3,
                           const float* bw, const float* Wm, const float* bm) {
  const int blk = (int)blockIdx.x, tid = (int)threadIdx.x;
  if (blk < 1600) {
    const int j = blk;
    f16* W1 = (f16*)(ws + OFF_W1) + (size_t)j * P1;
    f16* W2 = (f16*)(ws + OFF_W2) + (size_t)j * P2;
    f16* W3 = (f16*)(ws + OFF_W3) + (size_t)j * P2;
    for (int c = tid; c < P1; c += 256) {
      float v = 0.f;
      if (c < 64) v = Wih1[(size_t)j * 67 + 3 + c];
      else if (c < 464) v = Whh1[(size_t)j * 400 + c - 64];
      else if (c < 467) v = Wih1[(size_t)j * 67 + c - 464];
      W1[c] = (f16)v;
    }
    for (int c = tid; c < P2; c += 256) {
      float v2 = 0.f, v3 = 0.f;
      if (c < 64) { v2 = Wih2[(size_t)j * 467 + 403 + c]; v3 = Wih3[(size_t)j * 467 + 403 + c]; }
      else if (c < 464) { v2 = Wih2[(size_t)j * 467 + 3 + c - 64]; v3 = Wih3[(size_t)j * 467 + 3 + c - 64]; }
      else if (c < 467) { v2 = Wih2[(size_t)j * 467 + c - 464]; v3 = Wih3[(size_t)j * 467 + c - 464]; }
      else if (c >= 480 && c < 880) { v2 = Whh2[(size_t)j * 400 + c - 480]; v3 = Whh3[(size_t)j * 400 + c - 480]; }
      W2[c] = (f16)v2;
      W3[c] = (f16)v3;
    }
  } else if (blk < 1728) {
    const int r = blk - 1600;
    f16* WMp = (f16*)(ws + OFF_WM) + (size_t)r * PM;
    for (int c = tid; c < PM; c += 256) {
      const float v = (r < 121 && c < 1200) ? Wm[(size_t)r * 1200 + c] : 0.f;
      WMp[c] = (f16)v;
    }
  } else if (blk == 1728) {
    float* bs1 = (float*)(ws + OFF_BS1);
    float* bs2 = (float*)(ws + OFF_BS2);
    float* bs3 = (float*)(ws + OFF_BS3);
    for (int i = tid; i < 1600; i += 256) {
      bs1[i] = bih1[i] + bhh1[i];
      bs2[i] = bih2[i] + bhh2[i];
      bs3[i] = bih3[i] + bhh3[i];
    }
    float* bwp = (float*)(ws + OFF_BW);
    if (tid < 32) bwp[tid] = (tid < 30) ? bw[tid] : 0.f;
    float* bmp = (float*)(ws + OFF_BM);
    if (tid < 128) bmp[tid] = (tid < 121) ? bm[tid] : 0.f;
    unsigned* barr = (unsigned*)(ws + OFF_BAR);
    for (int i = tid; i < 2048; i += 256) barr[i] = 0u;
  } else if (blk < 1761) {
    unsigned* az = (unsigned*)(ws + OFF_A1);  // A1,A2,A3,AM contiguous
    const int n = (int)((SZ_A1 + 2 * SZ_A2 + SZ_AM) / 4);
    for (int i = (blk - 1729) * 256 + tid; i < n; i += 32 * 256) az[i] = 0u;
  } else {
    f16* tebp = (f16*)(ws + OFF_TEB);
    const int n = 64 * 96 * 64;
    for (int i = (blk - 1761) * 256 + tid; i < n; i += 128 * 256) {
      const int b = i / (96 * 64);
      const int rem = i % (96 * 64);
      const int u = rem >> 6, d = rem & 63;
      const int tk = tok[b * 96 + u];
      tebp[i] = (f16)emb[(size_t)tk * 64 + d];
    }
  }
}

__global__ void init_x0(char* ws, const float* x) {
  const int tid = (int)threadIdx.x;
  if (tid < 192) {
    const int b = tid / 3, k = tid % 3;
    const f16 xv = (f16)x[(size_t)b * Tn * 3 + k];
    ((f16*)(ws + OFF_A1))[(size_t)b * P1 + 464 + k] = xv;
    ((f16*)(ws + OFF_A2))[(size_t)b * P2 + 464 + k] = xv;
    ((f16*)(ws + OFF_A3))[(size_t)b * P3 + 464 + k] = xv;
  }
}

// ---- epilogue: res -> (eos, softmax pi, mu, sigma, rho) ----
__global__ void postproc(const char* ws, float* out) {
  __shared__ float r[50 * 128];
  __shared__ float mx[50], dn[50];
  const float* resb = (const float*)(ws + OFF_RES);
  const int tid = (int)threadIdx.x;
  const int b = (int)blockIdx.x >> 4;
  const int t0 = ((int)blockIdx.x & 15) * 50;
  for (int idx = tid; idx < 50 * 128; idx += 256) {
    const int tt = idx >> 7, c = idx & 127;
    r[idx] = resb[((size_t)(t0 + tt) * 64 + b) * 128 + c];
  }
  __syncthreads();
  if (tid < 50) {
    float m = -1e30f;
    for (int k = 0; k < 20; ++k) m = fmaxf(m, r[tid * 128 + 1 + k]);
    float s = 0.f;
    for (int k = 0; k < 20; ++k) s += expf(r[tid * 128 + 1 + k] - m);
    mx[tid] = m;
    dn[tid] = 1.f / s;
  }
  __syncthreads();
  for (int idx = tid; idx < 50; idx += 256)
    out[O_EOS + (size_t)b * Tn + t0 + idx] = r[idx * 128];
  for (int idx = tid; idx < 50 * 20; idx += 256) {
    const int tt = idx / 20, k = idx % 20;
    const size_t o = ((size_t)b * Tn + t0 + tt) * 20 + k;
    const float* rr = &r[tt * 128];
    out[O_PI + o] = expf(rr[1 + k] - mx[tt]) * dn[tt];
    out[O_MUX + o] = rr[21 + k];
    out[O_MUY + o] = rr[41 + k];
    out[O_SX + o] = expf(rr[61 + k]) + 1e-6f;
    out[O_SY + o] = expf(rr[81 + k]) + 1e-6f;
    out[O_RHO + o] = tanhf(rr[101 + k]) * 0.999f;
  }
}

extern "C" void kernel_launch(void* const* d_in, const int* in_sizes, int n_in,
                              void* d_out, int out_size, void* d_ws, size_t ws_size,
                              hipStream_t stream) {
  const float* x = (const float*)d_in[0];
  const int* tok = (const int*)d_in[1];
  const float* emb = (const float*)d_in[2];
  const float* Wih1 = (const float*)d_in[3];
  const float* Whh1 = (const float*)d_in[4];
  const float* bih1 = (const float*)d_in[5];
  const float* bhh1 = (const float*)d_in[6];
  const float* Wih2 = (const float*)d_in[7];
  const float* Whh2 = (const float*)d_in[8];
  const float* bih2 = (const float*)d_in[9];
  const float* bhh2 = (const float*)d_in[10];
  const float* Wih3 = (const float*)d_in[11];
  const float* Whh3 = (const float*)d_in[12];
  const float* bih3 = (const float*)d_in[13];
  const float* bhh3 = (const float*)d_in[14];
  const float* Ww = (const float*)d_in[15];
  const float* bw = (const float*)d_in[16];
  const float* Wm = (const float*)d_in[17];
  const float* bm = (const float*)d_in[18];
  char* ws = (char*)d_ws;
  float* out = (float*)d_out;

  hipLaunchKernelGGL(init_build, dim3(1889), dim3(256), 0, stream,
                     ws, tok, emb, Wih1, Whh1, bih1, bhh1, Wih2, Whh2, bih2, bhh2,
                     Wih3, Whh3, bih3, bhh3, bw, Wm, bm);
  hipLaunchKernelGGL(init_x0, dim3(1), dim3(256), 0, stream, ws, x);

  char* ws_arg = ws;
  const float* x_arg = x;
  const float* ww_arg = Ww;
  void* kargs[] = {&ws_arg, &x_arg, &ww_arg};
  hipError_t ce = hipLaunchCooperativeKernel((const void*)coop_kernel, dim3(NWG), dim3(256),
                                             kargs, 0, stream);
  if (ce != hipSuccess) {
    hipLaunchKernelGGL(coop_kernel, dim3(NWG), dim3(256), 0, stream, ws, x, Ww);
  }

  hipLaunchKernelGGL(postproc, dim3(1024), dim3(256), 0, stream, ws, out);
}

// Round 5
// 35196.500 us; speedup vs baseline: 1.6912x; 1.6912x over previous
//
#include <hip/hip_runtime.h>

// ============================================================================
// R5: R4's proven 3-phase lag schedule (A:{ATT(t),OUT(t-1)} B:{L2(t),L1(t+1)}
// C:{L3(t)}) + R3's proven coherence (plain cached loads/stores; barrier =
// release-RMW arrival + acquire-fence exit). 107 WGs, 2401 barriers.
// Label: "R5 = R4 schedule + R3 barrier/datapath"
// ============================================================================

#define DI __device__ __forceinline__

typedef _Float16 f16;
typedef _Float16 f16x8 __attribute__((ext_vector_type(8)));
typedef _Float16 f16x4 __attribute__((ext_vector_type(4)));
typedef float f32x4 __attribute__((ext_vector_type(4)));
typedef unsigned long long u64;

constexpr int Tn = 800, Un = 96, Hn = 400;
// K-layouts (f16, zero-padded to 32-multiples):
//  A1/W1: [w 64 | h1 400 | x 3 | 0..] P1=520, ks 0..15
//  A2/W2: [w 64 | h1 400 | x 3 | 0(13) | h2rec 400 | 0..] P2=904, ks 0..27
//  A3/W3: [w 64 | h2 400 | x 3 | 0(13) | h3rec 400 | 0..] P3=904, ks 0..27
//  AM/WM: [h1 400 | h2 400 | h3 400 | 0(88)] PM=1288, ks 0..39; AM x3 slots
constexpr int P1 = 520, P2 = 904, P3 = 904, PM = 1288, KPWM = 10;
constexpr int NWG = 107, NGRP = 8;

constexpr size_t OFF_W1 = 0;
constexpr size_t SZ_W1 = (size_t)1600 * P1 * 2;
constexpr size_t OFF_W2 = OFF_W1 + SZ_W1;
constexpr size_t SZ_W2 = (size_t)1600 * P2 * 2;
constexpr size_t OFF_W3 = OFF_W2 + SZ_W2;
constexpr size_t OFF_WM = OFF_W3 + SZ_W2;
constexpr size_t SZ_WM = (size_t)128 * PM * 2;
constexpr size_t OFF_A1 = OFF_WM + SZ_WM;
constexpr size_t SZ_A1 = (size_t)2 * 64 * P1 * 2;
constexpr size_t OFF_A2 = OFF_A1 + SZ_A1;
constexpr size_t SZ_A2 = (size_t)2 * 64 * P2 * 2;
constexpr size_t OFF_A3 = OFF_A2 + SZ_A2;
constexpr size_t OFF_AM = OFF_A3 + SZ_A2;
constexpr size_t SZ_AM = (size_t)3 * 64 * PM * 2;   // triple-buffered
constexpr size_t OFF_TEB = OFF_AM + SZ_AM;
constexpr size_t SZ_TEB = (size_t)64 * 96 * 64 * 2;
constexpr size_t OFF_BS1 = OFF_TEB + SZ_TEB;
constexpr size_t OFF_BS2 = OFF_BS1 + 6400;
constexpr size_t OFF_BS3 = OFF_BS2 + 6400;
constexpr size_t OFF_BW = OFF_BS3 + 6400;
constexpr size_t OFF_BM = OFF_BW + 128;
constexpr size_t OFF_BAR = OFF_BM + 512;
constexpr size_t SZ_BAR = 8192;
constexpr size_t OFF_RES = OFF_BAR + SZ_BAR;

// output offsets (fp32 elements): eos,pi,mux,muy,sx,sy,rho
constexpr size_t O_EOS = 0, O_PI = 51200, O_MUX = 1075200, O_MUY = 2099200;
constexpr size_t O_SX = 3123200, O_SY = 4147200, O_RHO = 5171200;

// ---- lean two-level grid barrier (R3-proven) ----
DI void gridbar(unsigned* barr) {
  __syncthreads();  // per-wave s_waitcnt vmcnt(0) before s_barrier: WG stores in L2
  if (threadIdx.x == 0) {
    const int g = (int)(blockIdx.x & (NGRP - 1));
    const unsigned gsz = (unsigned)((g < (NWG % NGRP)) ? (NWG / NGRP + 1) : (NWG / NGRP));
    unsigned* cnt = barr + g * 32;
    unsigned* root = barr + NGRP * 32;
    unsigned* gen = barr + (NGRP + 1) * 32;
    const unsigned old = __hip_atomic_load(gen, __ATOMIC_RELAXED, __HIP_MEMORY_SCOPE_AGENT);
    const unsigned a = __hip_atomic_fetch_add(cnt, 1u, __ATOMIC_RELEASE, __HIP_MEMORY_SCOPE_AGENT);
    if (a == gsz - 1u) {
      __builtin_amdgcn_fence(__ATOMIC_ACQUIRE, "agent");
      __hip_atomic_store(cnt, 0u, __ATOMIC_RELAXED, __HIP_MEMORY_SCOPE_AGENT);
      const unsigned ra = __hip_atomic_fetch_add(root, 1u, __ATOMIC_RELEASE, __HIP_MEMORY_SCOPE_AGENT);
      if (ra == (unsigned)(NGRP - 1)) {
        __builtin_amdgcn_fence(__ATOMIC_ACQUIRE, "agent");
        __hip_atomic_store(root, 0u, __ATOMIC_RELAXED, __HIP_MEMORY_SCOPE_AGENT);
        __hip_atomic_fetch_add(gen, 1u, __ATOMIC_RELEASE, __HIP_MEMORY_SCOPE_AGENT);
      }
    }
    int guard = 0;
    while (__hip_atomic_load(gen, __ATOMIC_RELAXED, __HIP_MEMORY_SCOPE_AGENT) == old) {
      __builtin_amdgcn_s_sleep(4);
      if (++guard > 20000000) break;  // failsafe
    }
  }
  __syncthreads();
  __builtin_amdgcn_fence(__ATOMIC_ACQUIRE, "agent");  // per-wave L1/L2 inv
}

DI float sigm(float v) { return 1.f / (1.f + expf(-v)); }

// ---- shared LSTM slot: wave-per-gate, m=64, j-tile=16; dC may be nullptr ----
template <int KS, int PITCH>
DI void lstm_slot(const f16x8* wr, const f16* Ain, char* smem, int tid,
                  const float* bL, float* cst,
                  f16* dA, int pA, f16* dB, int pB, f16* dC, int pC) {
  const int wave = tid >> 6, lane = tid & 63, ln16 = lane & 15, quad = lane >> 4;
  float* red = (float*)smem;  // [gate 4][b 64][j 16]
  f32x4 acc[4];
#pragma unroll
  for (int mt = 0; mt < 4; ++mt) acc[mt] = f32x4{0.f, 0.f, 0.f, 0.f};
#pragma unroll
  for (int i = 0; i < KS; ++i) {
    const int kc = i * 32 + quad * 8;
#pragma unroll
    for (int mt = 0; mt < 4; ++mt) {
      const f16x8 a = *(const f16x8*)(Ain + (mt * 16 + ln16) * PITCH + kc);
      acc[mt] = __builtin_amdgcn_mfma_f32_16x16x32_f16(a, wr[i], acc[mt], 0, 0, 0);
    }
  }
#pragma unroll
  for (int mt = 0; mt < 4; ++mt)
#pragma unroll
    for (int r = 0; r < 4; ++r)
      red[wave * 1024 + (mt * 16 + quad * 4 + r) * 16 + ln16] = acc[mt][r];
  __syncthreads();
  {
    const int oi = tid * 4, b = oi >> 4, j0 = oi & 15;
    f32x4 gi = *(f32x4*)&red[oi];
    f32x4 gf = *(f32x4*)&red[1024 + oi];
    f32x4 gg = *(f32x4*)&red[2048 + oi];
    f32x4 go = *(f32x4*)&red[3072 + oi];
    f32x4 c = *(f32x4*)&cst[oi];
    f16x4 hv;
#pragma unroll
    for (int e = 0; e < 4; ++e) {
      const float iv = sigm(gi[e] + bL[j0 + e]);
      const float fv = sigm(gf[e] + bL[16 + j0 + e]);
      const float gv = tanhf(gg[e] + bL[32 + j0 + e]);
      const float ov = sigm(go[e] + bL[48 + j0 + e]);
      const float cn = fv * c[e] + iv * gv;
      c[e] = cn;
      hv[e] = (f16)(ov * tanhf(cn));
    }
    *(f32x4*)&cst[oi] = c;
    *(f16x4*)(dA + b * pA + j0) = hv;
    *(f16x4*)(dB + b * pB + j0) = hv;
    if (dC != nullptr) *(f16x4*)(dC + b * pC + j0) = hv;
  }
  __syncthreads();
}

// ---- LSTM1 role (25 WGs): phase B computes L1(t+1); L1(0) pre-loop ----
DI void l1_role(char* ws, char* smem, int jb) {
  const int tid = threadIdx.x;
  const int wave = tid >> 6, lane = tid & 63, ln16 = lane & 15, quad = lane >> 4;
  const f16* W1 = (const f16*)(ws + OFF_W1);
  f16* A1 = (f16*)(ws + OFF_A1);
  f16* A2 = (f16*)(ws + OFF_A2);
  f16* AM = (f16*)(ws + OFF_AM);
  unsigned* barr = (unsigned*)(ws + OFF_BAR);
  float* cst = (float*)(smem + 16384);
  float* bL = (float*)(smem + 20480);
  const int row = wave * Hn + jb * 16 + ln16;
  f16x8 wr[16];
#pragma unroll
  for (int i = 0; i < 16; ++i) wr[i] = *(const f16x8*)(W1 + (size_t)row * P1 + i * 32 + quad * 8);
  if (tid < 64) bL[tid] = ((const float*)(ws + OFF_BS1))[(tid >> 4) * Hn + jb * 16 + (tid & 15)];
  for (int z = tid; z < 1024; z += 256) cst[z] = 0.f;
  __syncthreads();
  auto step = [&](int s) {
    lstm_slot<16, P1>(wr, A1 + (size_t)(s & 1) * 64 * P1, smem, tid, bL, cst,
                      A1 + (size_t)((s + 1) & 1) * 64 * P1 + 64 + jb * 16, P1,
                      A2 + (size_t)(s & 1) * 64 * P2 + 64 + jb * 16, P2,
                      AM + (size_t)(s % 3) * 64 * PM + jb * 16, PM);
  };
  step(0);
  gridbar(barr);
  for (int t = 0; t < Tn; ++t) {
    gridbar(barr);                 // end phase A
    if (t < Tn - 1) step(t + 1);   // phase B
    gridbar(barr);                 // end phase B
    gridbar(barr);                 // end phase C
  }
}

// ---- LSTM2 role (25 WGs): phase B computes L2(t) ----
DI void l2_role(char* ws, char* smem, int jb) {
  const int tid = threadIdx.x;
  const int wave = tid >> 6, lane = tid & 63, ln16 = lane & 15, quad = lane >> 4;
  const f16* W2 = (const f16*)(ws + OFF_W2);
  f16* A2 = (f16*)(ws + OFF_A2);
  f16* A3 = (f16*)(ws + OFF_A3);
  f16* AM = (f16*)(ws + OFF_AM);
  unsigned* barr = (unsigned*)(ws + OFF_BAR);
  float* cst = (float*)(smem + 16384);
  float* bL = (float*)(smem + 20480);
  const int row = wave * Hn + jb * 16 + ln16;
  f16x8 wr[28];
#pragma unroll
  for (int i = 0; i < 28; ++i) wr[i] = *(const f16x8*)(W2 + (size_t)row * P2 + i * 32 + quad * 8);
  if (tid < 64) bL[tid] = ((const float*)(ws + OFF_BS2))[(tid >> 4) * Hn + jb * 16 + (tid & 15)];
  for (int z = tid; z < 1024; z += 256) cst[z] = 0.f;
  __syncthreads();
  gridbar(barr);
  for (int t = 0; t < Tn; ++t) {
    gridbar(barr);                 // end phase A
    lstm_slot<28, P2>(wr, A2 + (size_t)(t & 1) * 64 * P2, smem, tid, bL, cst,
                      A2 + (size_t)((t + 1) & 1) * 64 * P2 + 480 + jb * 16, P2,
                      A3 + (size_t)(t & 1) * 64 * P3 + 64 + jb * 16, P3,
                      AM + (size_t)(t % 3) * 64 * PM + Hn + jb * 16, PM);
    gridbar(barr);                 // end phase B
    gridbar(barr);                 // end phase C
  }
}

// ---- LSTM3 role (25 WGs): phase C computes L3(t) ----
DI void l3_role(char* ws, char* smem, int jb) {
  const int tid = threadIdx.x;
  const int wave = tid >> 6, lane = tid & 63, ln16 = lane & 15, quad = lane >> 4;
  const f16* W3 = (const f16*)(ws + OFF_W3);
  f16* A3 = (f16*)(ws + OFF_A3);
  f16* AM = (f16*)(ws + OFF_AM);
  unsigned* barr = (unsigned*)(ws + OFF_BAR);
  float* cst = (float*)(smem + 16384);
  float* bL = (float*)(smem + 20480);
  const int row = wave * Hn + jb * 16 + ln16;
  f16x8 wr[28];
#pragma unroll
  for (int i = 0; i < 28; ++i) wr[i] = *(const f16x8*)(W3 + (size_t)row * P3 + i * 32 + quad * 8);
  if (tid < 64) bL[tid] = ((const float*)(ws + OFF_BS3))[(tid >> 4) * Hn + jb * 16 + (tid & 15)];
  for (int z = tid; z < 1024; z += 256) cst[z] = 0.f;
  __syncthreads();
  gridbar(barr);
  for (int t = 0; t < Tn; ++t) {
    gridbar(barr);                 // end phase A
    gridbar(barr);                 // end phase B
    lstm_slot<28, P3>(wr, A3 + (size_t)(t & 1) * 64 * P3, smem, tid, bL, cst,
                      A3 + (size_t)((t + 1) & 1) * 64 * P3 + 480 + jb * 16, P3,
                      AM + (size_t)(t % 3) * 64 * PM + 2 * Hn + jb * 16, PM,
                      nullptr, 0);
    gridbar(barr);                 // end phase C
  }
}

// ---- attention role (16 WGs x 4 batches): phase A computes ATT(t) ----
DI void att_role(char* ws, char* smem, int ab, const float* x, const float* Ww) {
  const int tid = threadIdx.x;
  const int b0 = ab * 4;
  f16* A1 = (f16*)(ws + OFF_A1);
  f16* A2 = (f16*)(ws + OFF_A2);
  f16* A3 = (f16*)(ws + OFF_A3);
  unsigned* barr = (unsigned*)(ws + OFF_BAR);
  f16* tebL = (f16*)smem;                 // 4*96*64 f16 = 49152
  f16* h1L = (f16*)(smem + 49152);        // 4*400 f16 = 3200
  float* ps = (float*)(smem + 52352);     // 960 f32
  float* pL = (float*)(smem + 56192);     // 120
  float* aL = (float*)(smem + 56672);     // 40
  float* beL = (float*)(smem + 56832);    // 40
  float* kaL = (float*)(smem + 56992);    // 40 (persistent kappa)
  float* phiL = (float*)(smem + 57152);   // 384
  float* bwL = (float*)(smem + 58688);    // 30
  f16* wL = (f16*)(smem + 58816);         // 256 f16 = 512B
  const int pr = tid >> 3, psd = tid & 7;
  float wwr[50];
  if (tid < 240) {
#pragma unroll
    for (int k = 0; k < 50; ++k) wwr[k] = Ww[pr * 400 + psd * 50 + k];
  }
  for (int i = tid; i < 24576; i += 256)
    tebL[i] = ((const f16*)(ws + OFF_TEB))[(size_t)b0 * 6144 + i];
  if (tid < 40) kaL[tid] = 0.f;
  if (tid < 30) bwL[tid] = ((const float*)(ws + OFF_BW))[tid];
  __syncthreads();

  gridbar(barr);
  for (int t = 0; t < Tn; ++t) {
    // ---- phase A: attention step t ----
    {
      const f16* h1p = A2 + (size_t)(t & 1) * 64 * P2;
      for (int i = tid; i < 400; i += 256) {   // 4 batches x 100 u64 chunks of h1
        const int b = i / 100, c = i % 100;
        ((u64*)h1L)[i] = *(const u64*)(h1p + (b0 + b) * P2 + 64 + c * 4);
      }
      __syncthreads();
      if (tid < 240) {
#pragma unroll 1
        for (int b = 0; b < 4; ++b) {
          const f16* hh = &h1L[b * 400 + psd * 50];
          float a = 0.f;
#pragma unroll
          for (int k = 0; k < 50; ++k) a += wwr[k] * (float)hh[k];
          ps[(b * 30 + pr) * 8 + psd] = a;
        }
      }
      __syncthreads();
      if (tid < 120) {
        const int b = tid / 30, r = tid % 30;
        float v = bwL[r];
#pragma unroll
        for (int s = 0; s < 8; ++s) v += ps[(b * 30 + r) * 8 + s];
        pL[b * 30 + r] = v;
      }
      __syncthreads();
      if (tid < 40) {
        const int b = tid / 10, k = tid % 10;
        aL[tid] = expf(pL[b * 30 + k]);
        beL[tid] = expf(pL[b * 30 + 10 + k]);
        kaL[tid] += expf(fminf(5.f, fmaxf(-10.f, pL[b * 30 + 20 + k])));
      }
      __syncthreads();
      for (int idx = tid; idx < 384; idx += 256) {
        const int b = idx / 96;
        const float u1 = (float)(idx % 96 + 1);
        float s = 0.f;
#pragma unroll
        for (int k = 0; k < 10; ++k) {
          const float d = kaL[b * 10 + k] - u1;
          s += aL[b * 10 + k] * expf(-beL[b * 10 + k] * d * d);
        }
        phiL[idx] = s;
      }
      __syncthreads();
      {
        const int b = tid >> 6, d = tid & 63;
        float wv = 0.f;
        for (int u = 0; u < 96; ++u) wv += phiL[b * 96 + u] * (float)tebL[(b * 96 + u) * 64 + d];
        wL[tid] = (f16)wv;
      }
      __syncthreads();
      if (tid < 64) {  // 8B-chunk stores of w(t)
        const u64 wq = ((u64*)wL)[tid];
        const int bg = b0 + (tid >> 4), d0 = (tid & 15) * 4;
        *(u64*)(A1 + (size_t)((t + 1) & 1) * 64 * P1 + bg * P1 + d0) = wq;  // L1(t+1)
        *(u64*)(A2 + (size_t)(t & 1) * 64 * P2 + bg * P2 + d0) = wq;        // L2(t)
        *(u64*)(A3 + (size_t)(t & 1) * 64 * P3 + bg * P3 + d0) = wq;        // L3(t)
      }
      if (t + 1 < Tn && tid < 4) {  // stage x(t+1) as one 8B chunk [x0,x1,x2,0]
        const int b = b0 + tid;
        const float* xp = x + ((size_t)b * Tn + (t + 1)) * 3;
        f16x4 xv = {(f16)xp[0], (f16)xp[1], (f16)xp[2], (f16)0.f};
        *(f16x4*)(A1 + (size_t)((t + 1) & 1) * 64 * P1 + b * P1 + 464) = xv;
        *(f16x4*)(A2 + (size_t)((t + 1) & 1) * 64 * P2 + b * P2 + 464) = xv;
        *(f16x4*)(A3 + (size_t)((t + 1) & 1) * 64 * P3 + b * P3 + 464) = xv;
      }
    }
    gridbar(barr);                 // end phase A
    gridbar(barr);                 // end phase B
    gridbar(barr);                 // end phase C
  }
}

// ---- output role (16 WGs): phase A computes OUT(t-1); tail OUT(Tn-1) ----
DI void out_role(char* ws, char* smem, int sub) {
  const int tid = threadIdx.x;
  const int wave = tid >> 6, lane = tid & 63, ln16 = lane & 15, quad = lane >> 4;
  const int mh = sub >> 3, nt = sub & 7;
  const int m0 = mh * 32;
  const f16* WM = (const f16*)(ws + OFF_WM);
  const f16* AM = (const f16*)(ws + OFF_AM);
  float* resb = (float*)(ws + OFF_RES);
  unsigned* barr = (unsigned*)(ws + OFF_BAR);
  float* red = (float*)smem;             // 8KB
  float* bmL = (float*)(smem + 8192);    // 16
  f16x8 wm[KPWM];
#pragma unroll
  for (int i = 0; i < KPWM; ++i) {
    const int ks = wave * KPWM + i;
    wm[i] = *(const f16x8*)(WM + (size_t)(nt * 16 + ln16) * PM + ks * 32 + quad * 8);
  }
  if (tid < 16) bmL[tid] = ((const float*)(ws + OFF_BM))[nt * 16 + tid];
  __syncthreads();

  auto step = [&](int s) {
    const f16* Ap = AM + (size_t)(s % 3) * 64 * PM;
    f32x4 acc[2];
    acc[0] = f32x4{0.f, 0.f, 0.f, 0.f};
    acc[1] = f32x4{0.f, 0.f, 0.f, 0.f};
#pragma unroll
    for (int i = 0; i < KPWM; ++i) {
      const int kc = (wave * KPWM + i) * 32 + quad * 8;
      const f16x8 a0 = *(const f16x8*)(Ap + (m0 + ln16) * PM + kc);
      const f16x8 a1 = *(const f16x8*)(Ap + (m0 + 16 + ln16) * PM + kc);
      acc[0] = __builtin_amdgcn_mfma_f32_16x16x32_f16(a0, wm[i], acc[0], 0, 0, 0);
      acc[1] = __builtin_amdgcn_mfma_f32_16x16x32_f16(a1, wm[i], acc[1], 0, 0, 0);
    }
#pragma unroll
    for (int mt = 0; mt < 2; ++mt)
      *(f32x4*)&red[((wave * 2 + mt) << 8) + (ln16 << 4) + (quad << 2)] = acc[mt];
    __syncthreads();
#pragma unroll
    for (int e = 0; e < 2; ++e) {
      const int oi = tid * 2 + e;
      const int m = oi & 31, cc = oi >> 5;
      const int mt = m >> 4, mr = m & 15;
      float v = bmL[cc];
#pragma unroll
      for (int wv = 0; wv < 4; ++wv) v += red[((wv * 2 + mt) << 8) + (cc << 4) + mr];
      resb[((size_t)s * 64 + m0 + m) * 128 + nt * 16 + cc] = v;
    }
    __syncthreads();
  };

  gridbar(barr);
  for (int t = 0; t < Tn; ++t) {
    if (t >= 1) step(t - 1);       // phase A
    gridbar(barr);                 // end phase A
    gridbar(barr);                 // end phase B
    gridbar(barr);                 // end phase C
  }
  step(Tn - 1);                    // tail: AM(Tn-1) complete since C(Tn-1)
}

__global__ void __launch_bounds__(256, 1) coop_kernel(char* ws, const float* x, const float* Ww) {
  __shared__ char smem[59392];
  const int id = (int)blockIdx.x;
  if (id < 25) l1_role(ws, smem, id);
  else if (id < 50) l2_role(ws, smem, id - 25);
  else if (id < 75) l3_role(ws, smem, id - 50);
  else if (id < 91) att_role(ws, smem, id - 75, x, Ww);
  else out_role(ws, smem, id - 91);
}

// ---- init: build f16 weight layouts, zero A-buffers, gather text emb ----
__global__ void init_build(char* ws, const int* tok, const float* emb,
                           const float* Wih1, const float* Whh1, const float* bih1, const float* bhh1,
                           const float* Wih2, const float* Whh2, const float* bih2, const float* bhh2,
                           const float* Wih3, const float* Whh3, const float* bih3, const float* bhh3,
                           const float* bw, const float* Wm, const float* bm) {
  const int blk = (int)blockIdx.x, tid = (int)threadIdx.x;
  if (blk < 1600) {
    const int j = blk;
    f16* W1 = (f16*)(ws + OFF_W1) + (size_t)j * P1;
    f16* W2 = (f16*)(ws + OFF_W2) + (size_t)j * P2;
    f16* W3 = (f16*)(ws + OFF_W3) + (size_t)j * P2;
    for (int c = tid; c < P1; c += 256) {
      float v = 0.f;
      if (c < 64) v = Wih1[(size_t)j * 67 + 3 + c];
      else if (c < 464) v = Whh1[(size_t)j * 400 + c - 64];
      else if (c < 467) v = Wih1[(size_t)j * 67 + c - 464];
      W1[c] = (f16)v;
    }
    for (int c = tid; c < P2; c += 256) {
      float v2 = 0.f, v3 = 0.f;
      if (c < 64) { v2 = Wih2[(size_t)j * 467 + 403 + c]; v3 = Wih3[(size_t)j * 467 + 403 + c]; }
      else if (c < 464) { v2 = Wih2[(size_t)j * 467 + 3 + c - 64]; v3 = Wih3[(size_t)j * 467 + 3 + c - 64]; }
      else if (c < 467) { v2 = Wih2[(size_t)j * 467 + c - 464]; v3 = Wih3[(size_t)j * 467 + c - 464]; }
      else if (c >= 480 && c < 880) { v2 = Whh2[(size_t)j * 400 + c - 480]; v3 = Whh3[(size_t)j * 400 + c - 480]; }
      W2[c] = (f16)v2;
      W3[c] = (f16)v3;
    }
  } else if (blk < 1728) {
    const int r = blk - 1600;
    f16* WMp = (f16*)(ws + OFF_WM) + (size_t)r * PM;
    for (int c = tid; c < PM; c += 256) {
      const float v = (r < 121 && c < 1200) ? Wm[(size_t)r * 1200 + c] : 0.f;
      WMp[c] = (f16)v;
    }
  } else if (blk == 1728) {
    float* bs1 = (float*)(ws + OFF_BS1);
    float* bs2 = (float*)(ws + OFF_BS2);
    float* bs3 = (float*)(ws + OFF_BS3);
    for (int i = tid; i < 1600; i += 256) {
      bs1[i] = bih1[i] + bhh1[i];
      bs2[i] = bih2[i] + bhh2[i];
      bs3[i] = bih3[i] + bhh3[i];
    }
    float* bwp = (float*)(ws + OFF_BW);
    if (tid < 32) bwp[tid] = (tid < 30) ? bw[tid] : 0.f;
    float* bmp = (float*)(ws + OFF_BM);
    if (tid < 128) bmp[tid] = (tid < 121) ? bm[tid] : 0.f;
    unsigned* barr = (unsigned*)(ws + OFF_BAR);
    for (int i = tid; i < 2048; i += 256) barr[i] = 0u;
  } else if (blk < 1761) {
    unsigned* az = (unsigned*)(ws + OFF_A1);  // A1,A2,A3,AM contiguous
    const int n = (int)((SZ_A1 + 2 * SZ_A2 + SZ_AM) / 4);
    for (int i = (blk - 1729) * 256 + tid; i < n; i += 32 * 256) az[i] = 0u;
  } else {
    f16* tebp = (f16*)(ws + OFF_TEB);
    const int n = 64 * 96 * 64;
    for (int i = (blk - 1761) * 256 + tid; i < n; i += 128 * 256) {
      const int b = i / (96 * 64);
      const int rem = i % (96 * 64);
      const int u = rem >> 6, d = rem & 63;
      const int tk = tok[b * 96 + u];
      tebp[i] = (f16)emb[(size_t)tk * 64 + d];
    }
  }
}

__global__ void init_x0(char* ws, const float* x) {
  const int tid = (int)threadIdx.x;
  if (tid < 192) {
    const int b = tid / 3, k = tid % 3;
    const f16 xv = (f16)x[(size_t)b * Tn * 3 + k];
    ((f16*)(ws + OFF_A1))[(size_t)b * P1 + 464 + k] = xv;
    ((f16*)(ws + OFF_A2))[(size_t)b * P2 + 464 + k] = xv;
    ((f16*)(ws + OFF_A3))[(size_t)b * P3 + 464 + k] = xv;
  }
}

// ---- epilogue: res -> (eos, softmax pi, mu, sigma, rho) ----
__global__ void postproc(const char* ws, float* out) {
  __shared__ float r[50 * 128];
  __shared__ float mx[50], dn[50];
  const float* resb = (const float*)(ws + OFF_RES);
  const int tid = (int)threadIdx.x;
  const int b = (int)blockIdx.x >> 4;
  const int t0 = ((int)blockIdx.x & 15) * 50;
  for (int idx = tid; idx < 50 * 128; idx += 256) {
    const int tt = idx >> 7, c = idx & 127;
    r[idx] = resb[((size_t)(t0 + tt) * 64 + b) * 128 + c];
  }
  __syncthreads();
  if (tid < 50) {
    float m = -1e30f;
    for (int k = 0; k < 20; ++k) m = fmaxf(m, r[tid * 128 + 1 + k]);
    float s = 0.f;
    for (int k = 0; k < 20; ++k) s += expf(r[tid * 128 + 1 + k] - m);
    mx[tid] = m;
    dn[tid] = 1.f / s;
  }
  __syncthreads();
  for (int idx = tid; idx < 50; idx += 256)
    out[O_EOS + (size_t)b * Tn + t0 + idx] = r[idx * 128];
  for (int idx = tid; idx < 50 * 20; idx += 256) {
    const int tt = idx / 20, k = idx % 20;
    const size_t o = ((size_t)b * Tn + t0 + tt) * 20 + k;
    const float* rr = &r[tt * 128];
    out[O_PI + o] = expf(rr[1 + k] - mx[tt]) * dn[tt];
    out[O_MUX + o] = rr[21 + k];
    out[O_MUY + o] = rr[41 + k];
    out[O_SX + o] = expf(rr[61 + k]) + 1e-6f;
    out[O_SY + o] = expf(rr[81 + k]) + 1e-6f;
    out[O_RHO + o] = tanhf(rr[101 + k]) * 0.999f;
  }
}

extern "C" void kernel_launch(void* const* d_in, const int* in_sizes, int n_in,
                              void* d_out, int out_size, void* d_ws, size_t ws_size,
                              hipStream_t stream) {
  const float* x = (const float*)d_in[0];
  const int* tok = (const int*)d_in[1];
  const float* emb = (const float*)d_in[2];
  const float* Wih1 = (const float*)d_in[3];
  const float* Whh1 = (const float*)d_in[4];
  const float* bih1 = (const float*)d_in[5];
  const float* bhh1 = (const float*)d_in[6];
  const float* Wih2 = (const float*)d_in[7];
  const float* Whh2 = (const float*)d_in[8];
  const float* bih2 = (const float*)d_in[9];
  const float* bhh2 = (const float*)d_in[10];
  const float* Wih3 = (const float*)d_in[11];
  const float* Whh3 = (const float*)d_in[12];
  const float* bih3 = (const float*)d_in[13];
  const float* bhh3 = (const float*)d_in[14];
  const float* Ww = (const float*)d_in[15];
  const float* bw = (const float*)d_in[16];
  const float* Wm = (const float*)d_in[17];
  const float* bm = (const float*)d_in[18];
  char* ws = (char*)d_ws;
  float* out = (float*)d_out;

  hipLaunchKernelGGL(init_build, dim3(1889), dim3(256), 0, stream,
                     ws, tok, emb, Wih1, Whh1, bih1, bhh1, Wih2, Whh2, bih2, bhh2,
                     Wih3, Whh3, bih3, bhh3, bw, Wm, bm);
  hipLaunchKernelGGL(init_x0, dim3(1), dim3(256), 0, stream, ws, x);

  char* ws_arg = ws;
  const float* x_arg = x;
  const float* ww_arg = Ww;
  void* kargs[] = {&ws_arg, &x_arg, &ww_arg};
  hipError_t ce = hipLaunchCooperativeKernel((const void*)coop_kernel, dim3(NWG), dim3(256),
                                             kargs, 0, stream);
  if (ce != hipSuccess) {
    hipLaunchKernelGGL(coop_kernel, dim3(NWG), dim3(256), 0, stream, ws, x, Ww);
  }

  hipLaunchKernelGGL(postproc, dim3(1024), dim3(256), 0, stream, ws, out);
}

// Round 7
// 14977.806 us; speedup vs baseline: 3.9741x; 2.3499x over previous
//
#include <hip/hip_runtime.h>

// ============================================================================
// R7: R6 dataflow (per-(role,step) monotonic flags, sc1 LLC datapath, LDS-
// staged A-tiles) with stage_chunk fixed: R6 staged only HALF the columns per
// chunk (256*KN u64 loaded vs 512*KN needed) -> MFMA read unwritten LDS -> NaN.
// Now each thread moves one 16B chunk (2 u64) per iter: 64 rows x KN*4 chunks.
// Label: "R7 = R6 + stage_chunk column fix"
// ============================================================================

#define DI __device__ __forceinline__

typedef _Float16 f16;
typedef _Float16 f16x8 __attribute__((ext_vector_type(8)));
typedef _Float16 f16x4 __attribute__((ext_vector_type(4)));
typedef float f32x4 __attribute__((ext_vector_type(4)));
typedef unsigned long long u64;

constexpr int Tn = 800, Un = 96, Hn = 400;
constexpr int P1 = 520, P2 = 904, P3 = 904, PM = 1288;
constexpr int NWG = 99;
constexpr int SP = 272;  // LDS staging pitch (f16)

constexpr size_t OFF_W1 = 0;
constexpr size_t SZ_W1 = (size_t)1600 * P1 * 2;
constexpr size_t OFF_W2 = OFF_W1 + SZ_W1;
constexpr size_t SZ_W2 = (size_t)1600 * P2 * 2;
constexpr size_t OFF_W3 = OFF_W2 + SZ_W2;
constexpr size_t OFF_WM = OFF_W3 + SZ_W2;
constexpr size_t SZ_WM = (size_t)128 * PM * 2;
constexpr size_t OFF_A1 = OFF_WM + SZ_WM;
constexpr size_t SZ_A1 = (size_t)2 * 64 * P1 * 2;
constexpr size_t OFF_A2 = OFF_A1 + SZ_A1;
constexpr size_t SZ_A2 = (size_t)2 * 64 * P2 * 2;
constexpr size_t OFF_A3 = OFF_A2 + SZ_A2;
constexpr size_t OFF_AM = OFF_A3 + SZ_A2;
constexpr size_t SZ_AM = (size_t)4 * 64 * PM * 2;   // quad-buffered (OUT lag)
constexpr size_t OFF_TEB = OFF_AM + SZ_AM;
constexpr size_t SZ_TEB = (size_t)64 * 96 * 64 * 2;
constexpr size_t OFF_BS1 = OFF_TEB + SZ_TEB;
constexpr size_t OFF_BS2 = OFF_BS1 + 6400;
constexpr size_t OFF_BS3 = OFF_BS2 + 6400;
constexpr size_t OFF_BW = OFF_BS3 + 6400;
constexpr size_t OFF_BM = OFF_BW + 128;
constexpr size_t OFF_FLG = OFF_BM + 512;
constexpr size_t SZ_FLG = (size_t)808 * 5 * 16 * 4;
constexpr size_t OFF_RES = OFF_FLG + SZ_FLG;

constexpr size_t O_EOS = 0, O_PI = 51200, O_MUX = 1075200, O_MUY = 2099200;
constexpr size_t O_SX = 3123200, O_SY = 4147200, O_RHO = 5171200;

#define RL1 0
#define RATT 1
#define RL2 2
#define RL3 3
#define ROUT 4
#define FLI(role, t) ((((t) + 8) * 5 + (role)) * 16)
constexpr unsigned TL1 = 25, TATT = 16, TL2 = 25, TL3 = 25, TOUT = 8;

// ---- sc1 LLC data movers ----
DI u64 ldU8(const f16* p) {
  return __hip_atomic_load((const u64*)p, __ATOMIC_RELAXED, __HIP_MEMORY_SCOPE_AGENT);
}
DI void stU8(f16* p, u64 u) {
  __hip_atomic_store((u64*)p, u, __ATOMIC_RELAXED, __HIP_MEMORY_SCOPE_AGENT);
}
DI void stA4(f16* p, f16x4 v) {
  union { f16x4 v; u64 u; } c; c.v = v;
  stU8(p, c.u);
}

// ---- flag wait (wave0 lanes poll in parallel) / arrive ----
DI void waitf(unsigned* flags, int* doom, int n,
              int l0, unsigned g0, int l1, unsigned g1, int l2, unsigned g2,
              int l3, unsigned g3, int l4, unsigned g4) {
  if (!*doom) {
    if (threadIdx.x < 64) {
      const int l = (int)threadIdx.x;
      int li = l0; unsigned tg = g0;
      if (l == 1) { li = l1; tg = g1; }
      else if (l == 2) { li = l2; tg = g2; }
      else if (l == 3) { li = l3; tg = g3; }
      else if (l == 4) { li = l4; tg = g4; }
      unsigned* p = flags + li;
      int ok = (l >= n) ? 1 : 0;
      int guard = 0;
      for (;;) {
        if (!ok) ok = (__hip_atomic_load(p, __ATOMIC_RELAXED, __HIP_MEMORY_SCOPE_AGENT) >= tg) ? 1 : 0;
        if (__all(ok)) break;
        __builtin_amdgcn_s_sleep(2);
        if (++guard > 2000000) { if (l == 0) *doom = 1; break; }  // fail visible, not hung
      }
    }
  }
  __syncthreads();
}
DI void arrive(unsigned* flags, int role, int t) {
  __syncthreads();  // all waves' sc1 stores drained (vmcnt0) before the add
  if (threadIdx.x == 0)
    __hip_atomic_fetch_add(flags + FLI(role, t), 1u, __ATOMIC_RELAXED, __HIP_MEMORY_SCOPE_AGENT);
}

DI float sigm(float v) { return 1.f / (1.f + expf(-v)); }

// ---- staged chunk (FIXED): 64 rows x KN ksteps; one 16B chunk per thread-iter
// total 16B chunks = 64 * KN*4 = 256*KN; r = i/(KN*4), c16 = i%(KN*4) ----
template <int KN>
DI void stage_chunk(const f16* Asrc, int pitch, f16* stg, int tid, int k0) {
  u64 lo[KN], hi[KN];
#pragma unroll
  for (int j = 0; j < KN; ++j) {
    const int i = tid + j * 256;
    const int r = i / (KN * 4), c16 = i % (KN * 4);
    const f16* p = Asrc + (size_t)r * pitch + k0 * 32 + c16 * 8;
    lo[j] = ldU8(p);
    hi[j] = ldU8(p + 4);
  }
  __syncthreads();  // previous chunk fully consumed before overwrite
#pragma unroll
  for (int j = 0; j < KN; ++j) {
    const int i = tid + j * 256;
    const int r = i / (KN * 4), c16 = i % (KN * 4);
    u64* q = (u64*)(stg + r * SP + c16 * 8);
    q[0] = lo[j];
    q[1] = hi[j];
  }
  __syncthreads();
}

// ---- LSTM core: stage+MFMA (wave-per-gate) + gates + h stores ----
template <int KS, int PITCH_>
DI void lstm_core(const f16x8* wr, const f16* Ain, f16* stg, float* red, float* cst,
                  const float* bL, int tid,
                  f16* dA, int pA, f16* dB, int pB, f16* dC, int pC) {
  const int wave = tid >> 6, lane = tid & 63, ln16 = lane & 15, quad = lane >> 4;
  f32x4 acc[4];
#pragma unroll
  for (int mt = 0; mt < 4; ++mt) acc[mt] = f32x4{0.f, 0.f, 0.f, 0.f};
  constexpr int NCH = (KS + 7) / 8;
#pragma unroll
  for (int ck = 0; ck < NCH; ++ck) {
    const int k0 = ck * 8;
    if (KS - k0 >= 8) {
      stage_chunk<8>(Ain, PITCH_, stg, tid, k0);
#pragma unroll
      for (int ksl = 0; ksl < 8; ++ksl) {
        const int kc = ksl * 32 + quad * 8;
#pragma unroll
        for (int mt = 0; mt < 4; ++mt) {
          const f16x8 a = *(const f16x8*)(stg + (mt * 16 + ln16) * SP + kc);
          acc[mt] = __builtin_amdgcn_mfma_f32_16x16x32_f16(a, wr[k0 + ksl], acc[mt], 0, 0, 0);
        }
      }
    } else {
      stage_chunk<4>(Ain, PITCH_, stg, tid, k0);
#pragma unroll
      for (int ksl = 0; ksl < 4; ++ksl) {
        const int kc = ksl * 32 + quad * 8;
#pragma unroll
        for (int mt = 0; mt < 4; ++mt) {
          const f16x8 a = *(const f16x8*)(stg + (mt * 16 + ln16) * SP + kc);
          acc[mt] = __builtin_amdgcn_mfma_f32_16x16x32_f16(a, wr[k0 + ksl], acc[mt], 0, 0, 0);
        }
      }
    }
  }
  // cross-wave gate exchange
#pragma unroll
  for (int mt = 0; mt < 4; ++mt)
#pragma unroll
    for (int r = 0; r < 4; ++r)
      red[wave * 1024 + (mt * 16 + quad * 4 + r) * 16 + ln16] = acc[mt][r];
  __syncthreads();
  {
    const int oi = tid * 4, b = oi >> 4, j0 = oi & 15;
    f32x4 gi = *(f32x4*)&red[oi];
    f32x4 gf = *(f32x4*)&red[1024 + oi];
    f32x4 gg = *(f32x4*)&red[2048 + oi];
    f32x4 go = *(f32x4*)&red[3072 + oi];
    f32x4 c = *(f32x4*)&cst[oi];
    f16x4 hv;
#pragma unroll
    for (int e = 0; e < 4; ++e) {
      const float iv = sigm(gi[e] + bL[j0 + e]);
      const float fv = sigm(gf[e] + bL[16 + j0 + e]);
      const float gv = tanhf(gg[e] + bL[32 + j0 + e]);
      const float ov = sigm(go[e] + bL[48 + j0 + e]);
      const float cn = fv * c[e] + iv * gv;
      c[e] = cn;
      hv[e] = (f16)(ov * tanhf(cn));
    }
    *(f32x4*)&cst[oi] = c;
    stA4(dA + b * pA + j0, hv);
    stA4(dB + b * pB + j0, hv);
    if (dC != nullptr) stA4(dC + b * pC + j0, hv);
  }
}

// ---- L1 role (25 WGs) ----
DI void l1_role(char* ws, char* smem, int jb, const float* x) {
  const int tid = threadIdx.x;
  const int wave = tid >> 6, lane = tid & 63, ln16 = lane & 15, quad = lane >> 4;
  const f16* W1 = (const f16*)(ws + OFF_W1);
  f16* A1 = (f16*)(ws + OFF_A1);
  f16* A2 = (f16*)(ws + OFF_A2);
  f16* A3 = (f16*)(ws + OFF_A3);
  f16* AM = (f16*)(ws + OFF_AM);
  unsigned* flg = (unsigned*)(ws + OFF_FLG);
  f16* stg = (f16*)smem;                    // 34816
  float* red = (float*)(smem + 34816);      // 16384
  float* cst = (float*)(smem + 51200);      // 4096
  float* bL = (float*)(smem + 55296);       // 256
  int* doom = (int*)(smem + 59384);
  const int row = wave * Hn + jb * 16 + ln16;
  f16x8 wr[16];
#pragma unroll
  for (int i = 0; i < 16; ++i) wr[i] = *(const f16x8*)(W1 + (size_t)row * P1 + i * 32 + quad * 8);
  if (tid < 64) bL[tid] = ((const float*)(ws + OFF_BS1))[(tid >> 4) * Hn + jb * 16 + (tid & 15)];
  for (int z = tid; z < 1024; z += 256) cst[z] = 0.f;
  if (tid == 0) *doom = 0;
  __syncthreads();
  for (int t = 0; t < Tn; ++t) {
    waitf(flg, doom, 5, FLI(RATT, t - 1), TATT, FLI(RL1, t - 1), TL1,
          FLI(RL2, t - 2), TL2, FLI(RL3, t - 2), TL3, FLI(ROUT, t - 4), TOUT);
    if (jb == 0 && tid < 64) {  // broadcast x(t) into A2/A3 current slot
      const float* xp = x + ((size_t)tid * Tn + t) * 3;
      f16x4 xv = {(f16)xp[0], (f16)xp[1], (f16)xp[2], (f16)0.f};
      stA4(A2 + (size_t)(t & 1) * 64 * P2 + tid * P2 + 464, xv);
      stA4(A3 + (size_t)(t & 1) * 64 * P3 + tid * P3 + 464, xv);
    }
    lstm_core<16, P1>(wr, A1 + (size_t)(t & 1) * 64 * P1, stg, red, cst, bL, tid,
                      A1 + (size_t)((t + 1) & 1) * 64 * P1 + 64 + jb * 16, P1,
                      A2 + (size_t)(t & 1) * 64 * P2 + 64 + jb * 16, P2,
                      AM + (size_t)(t & 3) * 64 * PM + jb * 16, PM);
    arrive(flg, RL1, t);
  }
}

// ---- L2 role (25 WGs) ----
DI void l2_role(char* ws, char* smem, int jb) {
  const int tid = threadIdx.x;
  const int wave = tid >> 6, lane = tid & 63, ln16 = lane & 15, quad = lane >> 4;
  const f16* W2 = (const f16*)(ws + OFF_W2);
  f16* A2 = (f16*)(ws + OFF_A2);
  f16* A3 = (f16*)(ws + OFF_A3);
  f16* AM = (f16*)(ws + OFF_AM);
  unsigned* flg = (unsigned*)(ws + OFF_FLG);
  f16* stg = (f16*)smem;
  float* red = (float*)(smem + 34816);
  float* cst = (float*)(smem + 51200);
  float* bL = (float*)(smem + 55296);
  int* doom = (int*)(smem + 59384);
  const int row = wave * Hn + jb * 16 + ln16;
  f16x8 wr[28];
#pragma unroll
  for (int i = 0; i < 28; ++i) wr[i] = *(const f16x8*)(W2 + (size_t)row * P2 + i * 32 + quad * 8);
  if (tid < 64) bL[tid] = ((const float*)(ws + OFF_BS2))[(tid >> 4) * Hn + jb * 16 + (tid & 15)];
  for (int z = tid; z < 1024; z += 256) cst[z] = 0.f;
  if (tid == 0) *doom = 0;
  __syncthreads();
  for (int t = 0; t < Tn; ++t) {
    waitf(flg, doom, 5, FLI(RATT, t), TATT, FLI(RL1, t), TL1,
          FLI(RL2, t - 1), TL2, FLI(RL3, t - 2), TL3, FLI(ROUT, t - 4), TOUT);
    lstm_core<28, P2>(wr, A2 + (size_t)(t & 1) * 64 * P2, stg, red, cst, bL, tid,
                      A2 + (size_t)((t + 1) & 1) * 64 * P2 + 480 + jb * 16, P2,
                      A3 + (size_t)(t & 1) * 64 * P3 + 64 + jb * 16, P3,
                      AM + (size_t)(t & 3) * 64 * PM + Hn + jb * 16, PM);
    arrive(flg, RL2, t);
  }
}

// ---- L3 role (25 WGs) ----
DI void l3_role(char* ws, char* smem, int jb) {
  const int tid = threadIdx.x;
  const int wave = tid >> 6, lane = tid & 63, ln16 = lane & 15, quad = lane >> 4;
  const f16* W3 = (const f16*)(ws + OFF_W3);
  f16* A3 = (f16*)(ws + OFF_A3);
  f16* AM = (f16*)(ws + OFF_AM);
  unsigned* flg = (unsigned*)(ws + OFF_FLG);
  f16* stg = (f16*)smem;
  float* red = (float*)(smem + 34816);
  float* cst = (float*)(smem + 51200);
  float* bL = (float*)(smem + 55296);
  int* doom = (int*)(smem + 59384);
  const int row = wave * Hn + jb * 16 + ln16;
  f16x8 wr[28];
#pragma unroll
  for (int i = 0; i < 28; ++i) wr[i] = *(const f16x8*)(W3 + (size_t)row * P3 + i * 32 + quad * 8);
  if (tid < 64) bL[tid] = ((const float*)(ws + OFF_BS3))[(tid >> 4) * Hn + jb * 16 + (tid & 15)];
  for (int z = tid; z < 1024; z += 256) cst[z] = 0.f;
  if (tid == 0) *doom = 0;
  __syncthreads();
  for (int t = 0; t < Tn; ++t) {
    waitf(flg, doom, 4, FLI(RATT, t), TATT, FLI(RL2, t), TL2,
          FLI(RL3, t - 1), TL3, FLI(ROUT, t - 4), TOUT, 0, 0);
    lstm_core<28, P3>(wr, A3 + (size_t)(t & 1) * 64 * P3, stg, red, cst, bL, tid,
                      A3 + (size_t)((t + 1) & 1) * 64 * P3 + 480 + jb * 16, P3,
                      AM + (size_t)(t & 3) * 64 * PM + 2 * Hn + jb * 16, PM,
                      nullptr, 0);
    arrive(flg, RL3, t);
  }
}

// ---- attention role (16 WGs x 4 batches) ----
DI void att_role(char* ws, char* smem, int ab, const float* x, const float* Ww) {
  const int tid = threadIdx.x;
  const int b0 = ab * 4;
  f16* A1 = (f16*)(ws + OFF_A1);
  f16* A2 = (f16*)(ws + OFF_A2);
  f16* A3 = (f16*)(ws + OFF_A3);
  unsigned* flg = (unsigned*)(ws + OFF_FLG);
  f16* tebL = (f16*)smem;                 // 49152
  f16* h1L = (f16*)(smem + 49152);        // 3200
  float* ps = (float*)(smem + 52352);     // 3840
  float* pL = (float*)(smem + 56192);     // 480
  float* aL = (float*)(smem + 56672);     // 160
  float* beL = (float*)(smem + 56832);    // 160
  float* kaL = (float*)(smem + 56992);    // 160 (persistent kappa)
  float* phiL = (float*)(smem + 57152);   // 1536
  float* bwL = (float*)(smem + 58688);    // 120
  f16* wL = (f16*)(smem + 58816);         // 512
  int* doom = (int*)(smem + 59384);
  const int pr = tid >> 3, psd = tid & 7;
  float wwr[50];
  if (tid < 240) {
#pragma unroll
    for (int k = 0; k < 50; ++k) wwr[k] = Ww[pr * 400 + psd * 50 + k];
  }
  for (int i = tid; i < 24576; i += 256)
    tebL[i] = ((const f16*)(ws + OFF_TEB))[(size_t)b0 * 6144 + i];
  if (tid < 40) kaL[tid] = 0.f;
  if (tid < 30) bwL[tid] = ((const float*)(ws + OFF_BW))[tid];
  if (tid == 0) *doom = 0;
  __syncthreads();

  for (int t = 0; t < Tn; ++t) {
    waitf(flg, doom, 3, FLI(RL1, t), TL1, FLI(RL2, t - 2), TL2,
          FLI(RL3, t - 2), TL3, 0, 0, 0, 0);
    {
      const f16* h1p = A2 + (size_t)(t & 1) * 64 * P2;
      for (int i = tid; i < 400; i += 256) {  // 4 batches x 100 u64 of h1 (sc1)
        const int b = i / 100, c = i % 100;
        ((u64*)h1L)[i] = ldU8(h1p + (b0 + b) * P2 + 64 + c * 4);
      }
      __syncthreads();
      if (tid < 240) {
#pragma unroll 1
        for (int b = 0; b < 4; ++b) {
          const f16* hh = &h1L[b * 400 + psd * 50];
          float a = 0.f;
#pragma unroll
          for (int k = 0; k < 50; ++k) a += wwr[k] * (float)hh[k];
          ps[(b * 30 + pr) * 8 + psd] = a;
        }
      }
      __syncthreads();
      if (tid < 120) {
        const int b = tid / 30, r = tid % 30;
        float v = bwL[r];
#pragma unroll
        for (int s = 0; s < 8; ++s) v += ps[(b * 30 + r) * 8 + s];
        pL[b * 30 + r] = v;
      }
      __syncthreads();
      if (tid < 40) {
        const int b = tid / 10, k = tid % 10;
        aL[tid] = expf(pL[b * 30 + k]);
        beL[tid] = expf(pL[b * 30 + 10 + k]);
        kaL[tid] += expf(fminf(5.f, fmaxf(-10.f, pL[b * 30 + 20 + k])));
      }
      __syncthreads();
      for (int idx = tid; idx < 384; idx += 256) {
        const int b = idx / 96;
        const float u1 = (float)(idx % 96 + 1);
        float s = 0.f;
#pragma unroll
        for (int k = 0; k < 10; ++k) {
          const float d = kaL[b * 10 + k] - u1;
          s += aL[b * 10 + k] * expf(-beL[b * 10 + k] * d * d);
        }
        phiL[idx] = s;
      }
      __syncthreads();
      {
        const int b = tid >> 6, d = tid & 63;
        float wv = 0.f;
        for (int u = 0; u < 96; ++u) wv += phiL[b * 96 + u] * (float)tebL[(b * 96 + u) * 64 + d];
        wL[tid] = (f16)wv;
      }
      __syncthreads();
      if (tid < 64) {  // w(t) -> L1(t+1), L2(t), L3(t)
        const u64 wq = ((u64*)wL)[tid];
        const int bg = b0 + (tid >> 4), d0 = (tid & 15) * 4;
        stU8(A1 + (size_t)((t + 1) & 1) * 64 * P1 + bg * P1 + d0, wq);
        stU8(A2 + (size_t)(t & 1) * 64 * P2 + bg * P2 + d0, wq);
        stU8(A3 + (size_t)(t & 1) * 64 * P3 + bg * P3 + d0, wq);
      }
      if (t + 1 < Tn && tid < 4) {  // stage x(t+1) into A1 next slot only
        const int b = b0 + tid;
        const float* xp = x + ((size_t)b * Tn + (t + 1)) * 3;
        f16x4 xv = {(f16)xp[0], (f16)xp[1], (f16)xp[2], (f16)0.f};
        stA4(A1 + (size_t)((t + 1) & 1) * 64 * P1 + b * P1 + 464, xv);
      }
    }
    arrive(flg, RATT, t);
  }
}

// ---- output role (8 WGs): wave-per-m16, full K=40 staged ----
DI void out_role(char* ws, char* smem, int nt) {
  const int tid = threadIdx.x;
  const int wave = tid >> 6, lane = tid & 63, ln16 = lane & 15, quad = lane >> 4;
  const f16* WM = (const f16*)(ws + OFF_WM);
  const f16* AM = (const f16*)(ws + OFF_AM);
  float* resb = (float*)(ws + OFF_RES);
  unsigned* flg = (unsigned*)(ws + OFF_FLG);
  f16* stg = (f16*)smem;                  // 34816
  float* bmL = (float*)(smem + 34816);    // 64
  int* doom = (int*)(smem + 59384);
  f16x8 wm[40];
#pragma unroll
  for (int i = 0; i < 40; ++i)
    wm[i] = *(const f16x8*)(WM + (size_t)(nt * 16 + ln16) * PM + i * 32 + quad * 8);
  if (tid < 16) bmL[tid] = ((const float*)(ws + OFF_BM))[nt * 16 + tid];
  if (tid == 0) *doom = 0;
  __syncthreads();

  for (int t = 0; t < Tn; ++t) {
    waitf(flg, doom, 3, FLI(RL1, t), TL1, FLI(RL2, t), TL2, FLI(RL3, t), TL3, 0, 0, 0, 0);
    const f16* Ap = AM + (size_t)(t & 3) * 64 * PM;
    f32x4 acc = f32x4{0.f, 0.f, 0.f, 0.f};
#pragma unroll
    for (int ck = 0; ck < 5; ++ck) {
      const int k0 = ck * 8;
      stage_chunk<8>(Ap, PM, stg, tid, k0);
#pragma unroll
      for (int ksl = 0; ksl < 8; ++ksl) {
        const f16x8 a = *(const f16x8*)(stg + (wave * 16 + ln16) * SP + ksl * 32 + quad * 8);
        acc = __builtin_amdgcn_mfma_f32_16x16x32_f16(a, wm[k0 + ksl], acc, 0, 0, 0);
      }
    }
#pragma unroll
    for (int e = 0; e < 4; ++e) {  // C-layout: col=lane&15, row=quad*4+e
      const int m = wave * 16 + quad * 4 + e;
      resb[((size_t)t * 64 + m) * 128 + nt * 16 + ln16] = acc[e] + bmL[ln16];
    }
    arrive(flg, ROUT, t);
  }
}

__global__ void __launch_bounds__(256, 1) coop_kernel(char* ws, const float* x, const float* Ww) {
  __shared__ char smem[59392];
  const int id = (int)blockIdx.x;
  if (id < 25) l1_role(ws, smem, id, x);
  else if (id < 50) l2_role(ws, smem, id - 25);
  else if (id < 75) l3_role(ws, smem, id - 50);
  else if (id < 91) att_role(ws, smem, id - 75, x, Ww);
  else out_role(ws, smem, id - 91);
}

// ---- init: f16 weight layouts, zero A-buffers, flags, text emb ----
__global__ void init_build(char* ws, const int* tok, const float* emb,
                           const float* Wih1, const float* Whh1, const float* bih1, const float* bhh1,
                           const float* Wih2, const float* Whh2, const float* bih2, const float* bhh2,
                           const float* Wih3, const float* Whh3, const float* bih3, const float* bhh3,
                           const float* bw, const float* Wm, const float* bm) {
  const int blk = (int)blockIdx.x, tid = (int)threadIdx.x;
  if (blk < 1600) {
    const int j = blk;
    f16* W1 = (f16*)(ws + OFF_W1) + (size_t)j * P1;
    f16* W2 = (f16*)(ws + OFF_W2) + (size_t)j * P2;
    f16* W3 = (f16*)(ws + OFF_W3) + (size_t)j * P2;
    for (int c = tid; c < P1; c += 256) {
      float v = 0.f;
      if (c < 64) v = Wih1[(size_t)j * 67 + 3 + c];
      else if (c < 464) v = Whh1[(size_t)j * 400 + c - 64];
      else if (c < 467) v = Wih1[(size_t)j * 67 + c - 464];
      W1[c] = (f16)v;
    }
    for (int c = tid; c < P2; c += 256) {
      float v2 = 0.f, v3 = 0.f;
      if (c < 64) { v2 = Wih2[(size_t)j * 467 + 403 + c]; v3 = Wih3[(size_t)j * 467 + 403 + c]; }
      else if (c < 464) { v2 = Wih2[(size_t)j * 467 + 3 + c - 64]; v3 = Wih3[(size_t)j * 467 + 3 + c - 64]; }
      else if (c < 467) { v2 = Wih2[(size_t)j * 467 + c - 464]; v3 = Wih3[(size_t)j * 467 + c - 464]; }
      else if (c >= 480 && c < 880) { v2 = Whh2[(size_t)j * 400 + c - 480]; v3 = Whh3[(size_t)j * 400 + c - 480]; }
      W2[c] = (f16)v2;
      W3[c] = (f16)v3;
    }
  } else if (blk < 1728) {
    const int r = blk - 1600;
    f16* WMp = (f16*)(ws + OFF_WM) + (size_t)r * PM;
    for (int c = tid; c < PM; c += 256) {
      const float v = (r < 121 && c < 1200) ? Wm[(size_t)r * 1200 + c] : 0.f;
      WMp[c] = (f16)v;
    }
  } else if (blk == 1728) {
    float* bs1 = (float*)(ws + OFF_BS1);
    float* bs2 = (float*)(ws + OFF_BS2);
    float* bs3 = (float*)(ws + OFF_BS3);
    for (int i = tid; i < 1600; i += 256) {
      bs1[i] = bih1[i] + bhh1[i];
      bs2[i] = bih2[i] + bhh2[i];
      bs3[i] = bih3[i] + bhh3[i];
    }
    float* bwp = (float*)(ws + OFF_BW);
    if (tid < 32) bwp[tid] = (tid < 30) ? bw[tid] : 0.f;
    float* bmp = (float*)(ws + OFF_BM);
    if (tid < 128) bmp[tid] = (tid < 121) ? bm[tid] : 0.f;
  } else if (blk == 1729) {
    unsigned* fl = (unsigned*)(ws + OFF_FLG);
    const int n = 808 * 5 * 16;
    for (int i = tid; i < n; i += 256) {
      const int line = i / 16;
      fl[i] = ((line / 5) < 8) ? 1000u : 0u;  // t<0 presets satisfied
    }
  } else if (blk < 1762) {
    unsigned* az = (unsigned*)(ws + OFF_A1);  // A1,A2,A3,AM contiguous
    const int n = (int)((SZ_A1 + 2 * SZ_A2 + SZ_AM) / 4);
    for (int i = (blk - 1730) * 256 + tid; i < n; i += 32 * 256) az[i] = 0u;
  } else {
    f16* tebp = (f16*)(ws + OFF_TEB);
    const int n = 64 * 96 * 64;
    for (int i = (blk - 1762) * 256 + tid; i < n; i += 128 * 256) {
      const int b = i / (96 * 64);
      const int rem = i % (96 * 64);
      const int u = rem >> 6, d = rem & 63;
      const int tk = tok[b * 96 + u];
      tebp[i] = (f16)emb[(size_t)tk * 64 + d];
    }
  }
}

__global__ void init_x0(char* ws, const float* x) {
  const int tid = (int)threadIdx.x;
  if (tid < 192) {
    const int b = tid / 3, k = tid % 3;
    ((f16*)(ws + OFF_A1))[(size_t)b * P1 + 464 + k] = (f16)x[(size_t)b * Tn * 3 + k];
  }
}

// ---- epilogue: res -> (eos, softmax pi, mu, sigma, rho) ----
__global__ void postproc(const char* ws, float* out) {
  __shared__ float r[50 * 128];
  __shared__ float mx[50], dn[50];
  const float* resb = (const float*)(ws + OFF_RES);
  const int tid = (int)threadIdx.x;
  const int b = (int)blockIdx.x >> 4;
  const int t0 = ((int)blockIdx.x & 15) * 50;
  for (int idx = tid; idx < 50 * 128; idx += 256) {
    const int tt = idx >> 7, c = idx & 127;
    r[idx] = resb[((size_t)(t0 + tt) * 64 + b) * 128 + c];
  }
  __syncthreads();
  if (tid < 50) {
    float m = -1e30f;
    for (int k = 0; k < 20; ++k) m = fmaxf(m, r[tid * 128 + 1 + k]);
    float s = 0.f;
    for (int k = 0; k < 20; ++k) s += expf(r[tid * 128 + 1 + k] - m);
    mx[tid] = m;
    dn[tid] = 1.f / s;
  }
  __syncthreads();
  for (int idx = tid; idx < 50; idx += 256)
    out[O_EOS + (size_t)b * Tn + t0 + idx] = r[idx * 128];
  for (int idx = tid; idx < 50 * 20; idx += 256) {
    const int tt = idx / 20, k = idx % 20;
    const size_t o = ((size_t)b * Tn + t0 + tt) * 20 + k;
    const float* rr = &r[tt * 128];
    out[O_PI + o] = expf(rr[1 + k] - mx[tt]) * dn[tt];
    out[O_MUX + o] = rr[21 + k];
    out[O_MUY + o] = rr[41 + k];
    out[O_SX + o] = expf(rr[61 + k]) + 1e-6f;
    out[O_SY + o] = expf(rr[81 + k]) + 1e-6f;
    out[O_RHO + o] = tanhf(rr[101 + k]) * 0.999f;
  }
}

extern "C" void kernel_launch(void* const* d_in, const int* in_sizes, int n_in,
                              void* d_out, int out_size, void* d_ws, size_t ws_size,
                              hipStream_t stream) {
  const float* x = (const float*)d_in[0];
  const int* tok = (const int*)d_in[1];
  const float* emb = (const float*)d_in[2];
  const float* Wih1 = (const float*)d_in[3];
  const float* Whh1 = (const float*)d_in[4];
  const float* bih1 = (const float*)d_in[5];
  const float* bhh1 = (const float*)d_in[6];
  const float* Wih2 = (const float*)d_in[7];
  const float* Whh2 = (const float*)d_in[8];
  const float* bih2 = (const float*)d_in[9];
  const float* bhh2 = (const float*)d_in[10];
  const float* Wih3 = (const float*)d_in[11];
  const float* Whh3 = (const float*)d_in[12];
  const float* bih3 = (const float*)d_in[13];
  const float* bhh3 = (const float*)d_in[14];
  const float* Ww = (const float*)d_in[15];
  const float* bw = (const float*)d_in[16];
  const float* Wm = (const float*)d_in[17];
  const float* bm = (const float*)d_in[18];
  char* ws = (char*)d_ws;
  float* out = (float*)d_out;

  hipLaunchKernelGGL(init_build, dim3(1890), dim3(256), 0, stream,
                     ws, tok, emb, Wih1, Whh1, bih1, bhh1, Wih2, Whh2, bih2, bhh2,
                     Wih3, Whh3, bih3, bhh3, bw, Wm, bm);
  hipLaunchKernelGGL(init_x0, dim3(1), dim3(256), 0, stream, ws, x);

  // 99 WGs <= 256 CUs: all co-resident under a plain launch; no grid barrier used
  hipLaunchKernelGGL(coop_kernel, dim3(NWG), dim3(256), 0, stream, ws, x, Ww);

  hipLaunchKernelGGL(postproc, dim3(1024), dim3(256), 0, stream, ws, out);
}

// Round 8
// 10720.147 us; speedup vs baseline: 5.5525x; 1.3972x over previous
//
#include <hip/hip_runtime.h>

// ============================================================================
// R8: dependency-ordered k-chunk phases. Each LSTM stages recurrent/upstream
// k-ranges under their own (early) flags; only w(+x) ksteps (2-3 of 16-28)
// sit behind the ATT flag on the critical L1<->ATT cycle. Datapath/flags = R7.
// Label: "R8 dep-ordered k-phases"
// ============================================================================

#define DI __device__ __forceinline__

typedef _Float16 f16;
typedef _Float16 f16x8 __attribute__((ext_vector_type(8)));
typedef _Float16 f16x4 __attribute__((ext_vector_type(4)));
typedef float f32x4 __attribute__((ext_vector_type(4)));
typedef unsigned long long u64;

constexpr int Tn = 800, Un = 96, Hn = 400;
constexpr int P1 = 520, P2 = 904, P3 = 904, PM = 1288;
constexpr int NWG = 99;
constexpr int SP = 272;  // LDS staging pitch (f16)

constexpr size_t OFF_W1 = 0;
constexpr size_t SZ_W1 = (size_t)1600 * P1 * 2;
constexpr size_t OFF_W2 = OFF_W1 + SZ_W1;
constexpr size_t SZ_W2 = (size_t)1600 * P2 * 2;
constexpr size_t OFF_W3 = OFF_W2 + SZ_W2;
constexpr size_t OFF_WM = OFF_W3 + SZ_W2;
constexpr size_t SZ_WM = (size_t)128 * PM * 2;
constexpr size_t OFF_A1 = OFF_WM + SZ_WM;
constexpr size_t SZ_A1 = (size_t)2 * 64 * P1 * 2;
constexpr size_t OFF_A2 = OFF_A1 + SZ_A1;
constexpr size_t SZ_A2 = (size_t)2 * 64 * P2 * 2;
constexpr size_t OFF_A3 = OFF_A2 + SZ_A2;
constexpr size_t OFF_AM = OFF_A3 + SZ_A2;
constexpr size_t SZ_AM = (size_t)4 * 64 * PM * 2;   // quad-buffered (OUT lag)
constexpr size_t OFF_TEB = OFF_AM + SZ_AM;
constexpr size_t SZ_TEB = (size_t)64 * 96 * 64 * 2;
constexpr size_t OFF_BS1 = OFF_TEB + SZ_TEB;
constexpr size_t OFF_BS2 = OFF_BS1 + 6400;
constexpr size_t OFF_BS3 = OFF_BS2 + 6400;
constexpr size_t OFF_BW = OFF_BS3 + 6400;
constexpr size_t OFF_BM = OFF_BW + 128;
constexpr size_t OFF_FLG = OFF_BM + 512;
constexpr size_t SZ_FLG = (size_t)808 * 5 * 16 * 4;
constexpr size_t OFF_RES = OFF_FLG + SZ_FLG;

constexpr size_t O_EOS = 0, O_PI = 51200, O_MUX = 1075200, O_MUY = 2099200;
constexpr size_t O_SX = 3123200, O_SY = 4147200, O_RHO = 5171200;

#define RL1 0
#define RATT 1
#define RL2 2
#define RL3 3
#define ROUT 4
#define FLI(role, t) ((((t) + 8) * 5 + (role)) * 16)
constexpr unsigned TL1 = 25, TATT = 16, TL2 = 25, TL3 = 25, TOUT = 8;

// ---- sc1 LLC data movers ----
DI u64 ldU8(const f16* p) {
  return __hip_atomic_load((const u64*)p, __ATOMIC_RELAXED, __HIP_MEMORY_SCOPE_AGENT);
}
DI void stU8(f16* p, u64 u) {
  __hip_atomic_store((u64*)p, u, __ATOMIC_RELAXED, __HIP_MEMORY_SCOPE_AGENT);
}
DI void stA4(f16* p, f16x4 v) {
  union { f16x4 v; u64 u; } c; c.v = v;
  stU8(p, c.u);
}

// ---- flag wait (wave0 lanes poll in parallel) / arrive ----
DI void waitf(unsigned* flags, int* doom, int n,
              int l0, unsigned g0, int l1, unsigned g1, int l2, unsigned g2,
              int l3, unsigned g3, int l4, unsigned g4) {
  if (!*doom) {
    if (threadIdx.x < 64) {
      const int l = (int)threadIdx.x;
      int li = l0; unsigned tg = g0;
      if (l == 1) { li = l1; tg = g1; }
      else if (l == 2) { li = l2; tg = g2; }
      else if (l == 3) { li = l3; tg = g3; }
      else if (l == 4) { li = l4; tg = g4; }
      unsigned* p = flags + li;
      int ok = (l >= n) ? 1 : 0;
      int guard = 0;
      for (;;) {
        if (!ok) ok = (__hip_atomic_load(p, __ATOMIC_RELAXED, __HIP_MEMORY_SCOPE_AGENT) >= tg) ? 1 : 0;
        if (__all(ok)) break;
        __builtin_amdgcn_s_sleep(1);
        if (++guard > 4000000) { if (l == 0) *doom = 1; break; }  // fail visible
      }
    }
  }
  __syncthreads();
}
DI void arrive(unsigned* flags, int role, int t) {
  __syncthreads();  // all waves' sc1 stores drained (vmcnt0) before the add
  if (threadIdx.x == 0)
    __hip_atomic_fetch_add(flags + FLI(role, t), 1u, __ATOMIC_RELAXED, __HIP_MEMORY_SCOPE_AGENT);
}

DI float sigm(float v) { return 1.f / (1.f + expf(-v)); }

// ---- stage KN ksteps (Ain pre-offset to kstep base) into stg cols [0,KN*32),
// then MFMA them (wave-per-gate), accumulating. 16B/thread-iter. ----
template <int KN, int PITCH_>
DI void mfma_ks(const f16x8* wr, const f16* Ain, f16* stg, int tid,
                int quad, int ln16, f32x4 acc[4]) {
  u64 lo[KN], hi[KN];
#pragma unroll
  for (int j = 0; j < KN; ++j) {
    const int i = tid + j * 256;
    const int r = i / (KN * 4), c16 = i % (KN * 4);
    const f16* p = Ain + (size_t)r * PITCH_ + c16 * 8;
    lo[j] = ldU8(p);
    hi[j] = ldU8(p + 4);
  }
  __syncthreads();  // previous range fully consumed before overwrite
#pragma unroll
  for (int j = 0; j < KN; ++j) {
    const int i = tid + j * 256;
    const int r = i / (KN * 4), c16 = i % (KN * 4);
    u64* q = (u64*)(stg + r * SP + c16 * 8);
    q[0] = lo[j];
    q[1] = hi[j];
  }
  __syncthreads();
#pragma unroll
  for (int ksl = 0; ksl < KN; ++ksl) {
    const int kc = ksl * 32 + quad * 8;
#pragma unroll
    for (int mt = 0; mt < 4; ++mt) {
      const f16x8 a = *(const f16x8*)(stg + (mt * 16 + ln16) * SP + kc);
      acc[mt] = __builtin_amdgcn_mfma_f32_16x16x32_f16(a, wr[ksl], acc[mt], 0, 0, 0);
    }
  }
}

// ---- gate finish: cross-wave reduce + LSTM nonlinearity + h stores ----
DI void gate_finish(f32x4 acc[4], float* red, float* cst, const float* bL, int tid,
                    int quad, int ln16, int wave,
                    f16* dA, int pA, f16* dB, int pB, f16* dC, int pC) {
#pragma unroll
  for (int mt = 0; mt < 4; ++mt)
#pragma unroll
    for (int r = 0; r < 4; ++r)
      red[wave * 1024 + (mt * 16 + quad * 4 + r) * 16 + ln16] = acc[mt][r];
  __syncthreads();
  {
    const int oi = tid * 4, b = oi >> 4, j0 = oi & 15;
    f32x4 gi = *(f32x4*)&red[oi];
    f32x4 gf = *(f32x4*)&red[1024 + oi];
    f32x4 gg = *(f32x4*)&red[2048 + oi];
    f32x4 go = *(f32x4*)&red[3072 + oi];
    f32x4 c = *(f32x4*)&cst[oi];
    f16x4 hv;
#pragma unroll
    for (int e = 0; e < 4; ++e) {
      const float iv = sigm(gi[e] + bL[j0 + e]);
      const float fv = sigm(gf[e] + bL[16 + j0 + e]);
      const float gv = tanhf(gg[e] + bL[32 + j0 + e]);
      const float ov = sigm(go[e] + bL[48 + j0 + e]);
      const float cn = fv * c[e] + iv * gv;
      c[e] = cn;
      hv[e] = (f16)(ov * tanhf(cn));
    }
    *(f32x4*)&cst[oi] = c;
    stA4(dA + b * pA + j0, hv);
    stA4(dB + b * pB + j0, hv);
    if (dC != nullptr) stA4(dC + b * pC + j0, hv);
  }
}

// ---- L1 role (25 WGs) ----
DI void l1_role(char* ws, char* smem, int jb, const float* x) {
  const int tid = threadIdx.x;
  const int wave = tid >> 6, lane = tid & 63, ln16 = lane & 15, quad = lane >> 4;
  const f16* W1 = (const f16*)(ws + OFF_W1);
  f16* A1 = (f16*)(ws + OFF_A1);
  f16* A2 = (f16*)(ws + OFF_A2);
  f16* A3 = (f16*)(ws + OFF_A3);
  f16* AM = (f16*)(ws + OFF_AM);
  unsigned* flg = (unsigned*)(ws + OFF_FLG);
  f16* stg = (f16*)smem;                    // 34816
  float* red = (float*)(smem + 34816);      // 16384
  float* cst = (float*)(smem + 51200);      // 4096
  float* bL = (float*)(smem + 55296);       // 256
  int* doom = (int*)(smem + 59384);
  const int row = wave * Hn + jb * 16 + ln16;
  f16x8 wr[16];
#pragma unroll
  for (int i = 0; i < 16; ++i) wr[i] = *(const f16x8*)(W1 + (size_t)row * P1 + i * 32 + quad * 8);
  if (tid < 64) bL[tid] = ((const float*)(ws + OFF_BS1))[(tid >> 4) * Hn + jb * 16 + (tid & 15)];
  for (int z = tid; z < 1024; z += 256) cst[z] = 0.f;
  if (tid == 0) *doom = 0;
  __syncthreads();
  for (int t = 0; t < Tn; ++t) {
    const f16* Ap = A1 + (size_t)(t & 1) * 64 * P1;
    f32x4 acc[4];
#pragma unroll
    for (int mt = 0; mt < 4; ++mt) acc[mt] = f32x4{0.f, 0.f, 0.f, 0.f};
    // phase A: h1 rec ks2..13 (needs only own role t-1)
    waitf(flg, doom, 1, FLI(RL1, t - 1), TL1, 0, 0, 0, 0, 0, 0, 0, 0);
    mfma_ks<8, P1>(wr + 2, Ap + 2 * 32, stg, tid, quad, ln16, acc);
    mfma_ks<4, P1>(wr + 10, Ap + 10 * 32, stg, tid, quad, ln16, acc);
    // phase B: w + x (ks0,1,14) after ATT(t-1); WAR flags for our writes
    waitf(flg, doom, 4, FLI(RATT, t - 1), TATT, FLI(RL2, t - 2), TL2,
          FLI(RL3, t - 2), TL3, FLI(ROUT, t - 4), TOUT, 0, 0);
    if (jb == 0 && tid < 64) {  // broadcast x(t) into A2/A3 current slot
      const float* xp = x + ((size_t)tid * Tn + t) * 3;
      f16x4 xv = {(f16)xp[0], (f16)xp[1], (f16)xp[2], (f16)0.f};
      stA4(A2 + (size_t)(t & 1) * 64 * P2 + tid * P2 + 464, xv);
      stA4(A3 + (size_t)(t & 1) * 64 * P3 + tid * P3 + 464, xv);
    }
    mfma_ks<2, P1>(wr + 0, Ap + 0, stg, tid, quad, ln16, acc);
    mfma_ks<1, P1>(wr + 14, Ap + 14 * 32, stg, tid, quad, ln16, acc);
    // ks15 = pure zero padding: skipped
    gate_finish(acc, red, cst, bL, tid, quad, ln16, wave,
                A1 + (size_t)((t + 1) & 1) * 64 * P1 + 64 + jb * 16, P1,
                A2 + (size_t)(t & 1) * 64 * P2 + 64 + jb * 16, P2,
                AM + (size_t)(t & 3) * 64 * PM + jb * 16, PM);
    arrive(flg, RL1, t);
  }
}

// ---- L2 role (25 WGs) ----
DI void l2_role(char* ws, char* smem, int jb) {
  const int tid = threadIdx.x;
  const int wave = tid >> 6, lane = tid & 63, ln16 = lane & 15, quad = lane >> 4;
  const f16* W2 = (const f16*)(ws + OFF_W2);
  f16* A2 = (f16*)(ws + OFF_A2);
  f16* A3 = (f16*)(ws + OFF_A3);
  f16* AM = (f16*)(ws + OFF_AM);
  unsigned* flg = (unsigned*)(ws + OFF_FLG);
  f16* stg = (f16*)smem;
  float* red = (float*)(smem + 34816);
  float* cst = (float*)(smem + 51200);
  float* bL = (float*)(smem + 55296);
  int* doom = (int*)(smem + 59384);
  const int row = wave * Hn + jb * 16 + ln16;
  f16x8 wr[28];
#pragma unroll
  for (int i = 0; i < 28; ++i) wr[i] = *(const f16x8*)(W2 + (size_t)row * P2 + i * 32 + quad * 8);
  if (tid < 64) bL[tid] = ((const float*)(ws + OFF_BS2))[(tid >> 4) * Hn + jb * 16 + (tid & 15)];
  for (int z = tid; z < 1024; z += 256) cst[z] = 0.f;
  if (tid == 0) *doom = 0;
  __syncthreads();
  for (int t = 0; t < Tn; ++t) {
    const f16* Ap = A2 + (size_t)(t & 1) * 64 * P2;
    f32x4 acc[4];
#pragma unroll
    for (int mt = 0; mt < 4; ++mt) acc[mt] = f32x4{0.f, 0.f, 0.f, 0.f};
    // phase A: h2rec ks15..27 (own role t-1)
    waitf(flg, doom, 1, FLI(RL2, t - 1), TL2, 0, 0, 0, 0, 0, 0, 0, 0);
    mfma_ks<8, P2>(wr + 15, Ap + 15 * 32, stg, tid, quad, ln16, acc);
    mfma_ks<5, P2>(wr + 23, Ap + 23 * 32, stg, tid, quad, ln16, acc);
    // phase B: h1 + x ks2..14 (needs L1(t))
    waitf(flg, doom, 1, FLI(RL1, t), TL1, 0, 0, 0, 0, 0, 0, 0, 0);
    mfma_ks<8, P2>(wr + 2, Ap + 2 * 32, stg, tid, quad, ln16, acc);
    mfma_ks<5, P2>(wr + 10, Ap + 10 * 32, stg, tid, quad, ln16, acc);
    // phase C: w ks0..1 (needs ATT(t)); WAR flags for our writes
    waitf(flg, doom, 3, FLI(RATT, t), TATT, FLI(RL3, t - 2), TL3,
          FLI(ROUT, t - 4), TOUT, 0, 0, 0, 0);
    mfma_ks<2, P2>(wr + 0, Ap + 0, stg, tid, quad, ln16, acc);
    gate_finish(acc, red, cst, bL, tid, quad, ln16, wave,
                A2 + (size_t)((t + 1) & 1) * 64 * P2 + 480 + jb * 16, P2,
                A3 + (size_t)(t & 1) * 64 * P3 + 64 + jb * 16, P3,
                AM + (size_t)(t & 3) * 64 * PM + Hn + jb * 16, PM);
    arrive(flg, RL2, t);
  }
}

// ---- L3 role (25 WGs) ----
DI void l3_role(char* ws, char* smem, int jb) {
  const int tid = threadIdx.x;
  const int wave = tid >> 6, lane = tid & 63, ln16 = lane & 15, quad = lane >> 4;
  const f16* W3 = (const f16*)(ws + OFF_W3);
  f16* A3 = (f16*)(ws + OFF_A3);
  f16* AM = (f16*)(ws + OFF_AM);
  unsigned* flg = (unsigned*)(ws + OFF_FLG);
  f16* stg = (f16*)smem;
  float* red = (float*)(smem + 34816);
  float* cst = (float*)(smem + 51200);
  float* bL = (float*)(smem + 55296);
  int* doom = (int*)(smem + 59384);
  const int row = wave * Hn + jb * 16 + ln16;
  f16x8 wr[28];
#pragma unroll
  for (int i = 0; i < 28; ++i) wr[i] = *(const f16x8*)(W3 + (size_t)row * P3 + i * 32 + quad * 8);
  if (tid < 64) bL[tid] = ((const float*)(ws + OFF_BS3))[(tid >> 4) * Hn + jb * 16 + (tid & 15)];
  for (int z = tid; z < 1024; z += 256) cst[z] = 0.f;
  if (tid == 0) *doom = 0;
  __syncthreads();
  for (int t = 0; t < Tn; ++t) {
    const f16* Ap = A3 + (size_t)(t & 1) * 64 * P3;
    f32x4 acc[4];
#pragma unroll
    for (int mt = 0; mt < 4; ++mt) acc[mt] = f32x4{0.f, 0.f, 0.f, 0.f};
    // phase A: h3rec ks15..27 (own role t-1)
    waitf(flg, doom, 1, FLI(RL3, t - 1), TL3, 0, 0, 0, 0, 0, 0, 0, 0);
    mfma_ks<8, P3>(wr + 15, Ap + 15 * 32, stg, tid, quad, ln16, acc);
    mfma_ks<5, P3>(wr + 23, Ap + 23 * 32, stg, tid, quad, ln16, acc);
    // phase B: h2 + x ks2..14 (needs L2(t); x under RL1(t) < RL2(t) temporally)
    waitf(flg, doom, 1, FLI(RL2, t), TL2, 0, 0, 0, 0, 0, 0, 0, 0);
    mfma_ks<8, P3>(wr + 2, Ap + 2 * 32, stg, tid, quad, ln16, acc);
    mfma_ks<5, P3>(wr + 10, Ap + 10 * 32, stg, tid, quad, ln16, acc);
    // phase C: w ks0..1 (needs ATT(t)); WAR for AM write
    waitf(flg, doom, 2, FLI(RATT, t), TATT, FLI(ROUT, t - 4), TOUT, 0, 0, 0, 0, 0, 0);
    mfma_ks<2, P3>(wr + 0, Ap + 0, stg, tid, quad, ln16, acc);
    gate_finish(acc, red, cst, bL, tid, quad, ln16, wave,
                A3 + (size_t)((t + 1) & 1) * 64 * P3 + 480 + jb * 16, P3,
                AM + (size_t)(t & 3) * 64 * PM + 2 * Hn + jb * 16, PM,
                nullptr, 0);
    arrive(flg, RL3, t);
  }
}

// ---- attention role (16 WGs x 4 batches) ----
DI void att_role(char* ws, char* smem, int ab, const float* x, const float* Ww) {
  const int tid = threadIdx.x;
  const int b0 = ab * 4;
  f16* A1 = (f16*)(ws + OFF_A1);
  f16* A2 = (f16*)(ws + OFF_A2);
  f16* A3 = (f16*)(ws + OFF_A3);
  unsigned* flg = (unsigned*)(ws + OFF_FLG);
  f16* tebL = (f16*)smem;                 // 49152
  f16* h1L = (f16*)(smem + 49152);        // 3200
  float* ps = (float*)(smem + 52352);     // 3840
  float* pL = (float*)(smem + 56192);     // 480
  float* aL = (float*)(smem + 56672);     // 160
  float* beL = (float*)(smem + 56832);    // 160
  float* kaL = (float*)(smem + 56992);    // 160 (persistent kappa)
  float* phiL = (float*)(smem + 57152);   // 1536
  float* bwL = (float*)(smem + 58688);    // 120
  f16* wL = (f16*)(smem + 58816);         // 512
  int* doom = (int*)(smem + 59384);
  const int pr = tid >> 3, psd = tid & 7;
  float wwr[50];
  if (tid < 240) {
#pragma unroll
    for (int k = 0; k < 50; ++k) wwr[k] = Ww[pr * 400 + psd * 50 + k];
  }
  for (int i = tid; i < 24576; i += 256)
    tebL[i] = ((const f16*)(ws + OFF_TEB))[(size_t)b0 * 6144 + i];
  if (tid < 40) kaL[tid] = 0.f;
  if (tid < 30) bwL[tid] = ((const float*)(ws + OFF_BW))[tid];
  if (tid == 0) *doom = 0;
  __syncthreads();

  for (int t = 0; t < Tn; ++t) {
    waitf(flg, doom, 3, FLI(RL1, t), TL1, FLI(RL2, t - 2), TL2,
          FLI(RL3, t - 2), TL3, 0, 0, 0, 0);
    {
      const f16* h1p = A2 + (size_t)(t & 1) * 64 * P2;
      for (int i = tid; i < 400; i += 256) {  // 4 batches x 100 u64 of h1 (sc1)
        const int b = i / 100, c = i % 100;
        ((u64*)h1L)[i] = ldU8(h1p + (b0 + b) * P2 + 64 + c * 4);
      }
      __syncthreads();
      if (tid < 240) {
#pragma unroll 1
        for (int b = 0; b < 4; ++b) {
          const f16* hh = &h1L[b * 400 + psd * 50];
          float a = 0.f;
#pragma unroll
          for (int k = 0; k < 50; ++k) a += wwr[k] * (float)hh[k];
          ps[(b * 30 + pr) * 8 + psd] = a;
        }
      }
      __syncthreads();
      if (tid < 120) {
        const int b = tid / 30, r = tid % 30;
        float v = bwL[r];
#pragma unroll
        for (int s = 0; s < 8; ++s) v += ps[(b * 30 + r) * 8 + s];
        pL[b * 30 + r] = v;
      }
      __syncthreads();
      if (tid < 40) {
        const int b = tid / 10, k = tid % 10;
        aL[tid] = expf(pL[b * 30 + k]);
        beL[tid] = expf(pL[b * 30 + 10 + k]);
        kaL[tid] += expf(fminf(5.f, fmaxf(-10.f, pL[b * 30 + 20 + k])));
      }
      __syncthreads();
      for (int idx = tid; idx < 384; idx += 256) {
        const int b = idx / 96;
        const float u1 = (float)(idx % 96 + 1);
        float s = 0.f;
#pragma unroll
        for (int k = 0; k < 10; ++k) {
          const float d = kaL[b * 10 + k] - u1;
          s += aL[b * 10 + k] * expf(-beL[b * 10 + k] * d * d);
        }
        phiL[idx] = s;
      }
      __syncthreads();
      {
        const int b = tid >> 6, d = tid & 63;
        float wv = 0.f;
        for (int u = 0; u < 96; ++u) wv += phiL[b * 96 + u] * (float)tebL[(b * 96 + u) * 64 + d];
        wL[tid] = (f16)wv;
      }
      __syncthreads();
      if (tid < 64) {  // w(t) -> L1(t+1), L2(t), L3(t)
        const u64 wq = ((u64*)wL)[tid];
        const int bg = b0 + (tid >> 4), d0 = (tid & 15) * 4;
        stU8(A1 + (size_t)((t + 1) & 1) * 64 * P1 + bg * P1 + d0, wq);
        stU8(A2 + (size_t)(t & 1) * 64 * P2 + bg * P2 + d0, wq);
        stU8(A3 + (size_t)(t & 1) * 64 * P3 + bg * P3 + d0, wq);
      }
      if (t + 1 < Tn && tid < 4) {  // stage x(t+1) into A1 next slot only
        const int b = b0 + tid;
        const float* xp = x + ((size_t)b * Tn + (t + 1)) * 3;
        f16x4 xv = {(f16)xp[0], (f16)xp[1], (f16)xp[2], (f16)0.f};
        stA4(A1 + (size_t)((t + 1) & 1) * 64 * P1 + b * P1 + 464, xv);
      }
    }
    arrive(flg, RATT, t);
  }
}

// ---- output role (8 WGs): wave-per-m16, K=40 (pad ks38-39 skipped) ----
DI void out_role(char* ws, char* smem, int nt) {
  const int tid = threadIdx.x;
  const int wave = tid >> 6, lane = tid & 63, ln16 = lane & 15, quad = lane >> 4;
  const f16* WM = (const f16*)(ws + OFF_WM);
  const f16* AM = (const f16*)(ws + OFF_AM);
  float* resb = (float*)(ws + OFF_RES);
  unsigned* flg = (unsigned*)(ws + OFF_FLG);
  f16* stg = (f16*)smem;                  // 34816
  float* bmL = (float*)(smem + 34816);    // 64
  int* doom = (int*)(smem + 59384);
  f16x8 wm[38];
#pragma unroll
  for (int i = 0; i < 38; ++i)
    wm[i] = *(const f16x8*)(WM + (size_t)(nt * 16 + ln16) * PM + i * 32 + quad * 8);
  if (tid < 16) bmL[tid] = ((const float*)(ws + OFF_BM))[nt * 16 + tid];
  if (tid == 0) *doom = 0;
  __syncthreads();

  for (int t = 0; t < Tn; ++t) {
    waitf(flg, doom, 3, FLI(RL1, t), TL1, FLI(RL2, t), TL2, FLI(RL3, t), TL3, 0, 0, 0, 0);
    const f16* Ap = AM + (size_t)(t & 3) * 64 * PM;
    f32x4 acc = f32x4{0.f, 0.f, 0.f, 0.f};
    // stage+mfma 38 ksteps in sub-chunks (wave handles m16 = wave*16)
#pragma unroll
    for (int ck = 0; ck < 5; ++ck) {
      const int k0 = ck * 8;
      const int kn = (ck < 4) ? 8 : 6;
      // inline stage (runtime kn<=8): 16B per thread-iter
      u64 lo[8], hi[8];
      for (int j = 0; j < kn; ++j) {
        const int i = tid + j * 256;
        const int r = i / (kn * 4), c16 = i % (kn * 4);
        const f16* p = Ap + (size_t)r * PM + k0 * 32 + c16 * 8;
        lo[j] = ldU8(p);
        hi[j] = ldU8(p + 4);
      }
      __syncthreads();
      for (int j = 0; j < kn; ++j) {
        const int i = tid + j * 256;
        const int r = i / (kn * 4), c16 = i % (kn * 4);
        u64* q = (u64*)(stg + r * SP + c16 * 8);
        q[0] = lo[j];
        q[1] = hi[j];
      }
      __syncthreads();
      for (int ksl = 0; ksl < kn; ++ksl) {
        const f16x8 a = *(const f16x8*)(stg + (wave * 16 + ln16) * SP + ksl * 32 + quad * 8);
        acc = __builtin_amdgcn_mfma_f32_16x16x32_f16(a, wm[k0 + ksl], acc, 0, 0, 0);
      }
    }
#pragma unroll
    for (int e = 0; e < 4; ++e) {  // C-layout: col=lane&15, row=quad*4+e
      const int m = wave * 16 + quad * 4 + e;
      resb[((size_t)t * 64 + m) * 128 + nt * 16 + ln16] = acc[e] + bmL[ln16];
    }
    arrive(flg, ROUT, t);
  }
}

__global__ void __launch_bounds__(256, 1) coop_kernel(char* ws, const float* x, const float* Ww) {
  __shared__ char smem[59392];
  const int id = (int)blockIdx.x;
  if (id < 25) l1_role(ws, smem, id, x);
  else if (id < 50) l2_role(ws, smem, id - 25);
  else if (id < 75) l3_role(ws, smem, id - 50);
  else if (id < 91) att_role(ws, smem, id - 75, x, Ww);
  else out_role(ws, smem, id - 91);
}

// ---- init: f16 weight layouts, zero A-buffers, flags, text emb ----
__global__ void init_build(char* ws, const int* tok, const float* emb,
                           const float* Wih1, const float* Whh1, const float* bih1, const float* bhh1,
                           const float* Wih2, const float* Whh2, const float* bih2, const float* bhh2,
                           const float* Wih3, const float* Whh3, const float* bih3, const float* bhh3,
                           const float* bw, const float* Wm, const float* bm) {
  const int blk = (int)blockIdx.x, tid = (int)threadIdx.x;
  if (blk < 1600) {
    const int j = blk;
    f16* W1 = (f16*)(ws + OFF_W1) + (size_t)j * P1;
    f16* W2 = (f16*)(ws + OFF_W2) + (size_t)j * P2;
    f16* W3 = (f16*)(ws + OFF_W3) + (size_t)j * P2;
    for (int c = tid; c < P1; c += 256) {
      float v = 0.f;
      if (c < 64) v = Wih1[(size_t)j * 67 + 3 + c];
      else if (c < 464) v = Whh1[(size_t)j * 400 + c - 64];
      else if (c < 467) v = Wih1[(size_t)j * 67 + c - 464];
      W1[c] = (f16)v;
    }
    for (int c = tid; c < P2; c += 256) {
      float v2 = 0.f, v3 = 0.f;
      if (c < 64) { v2 = Wih2[(size_t)j * 467 + 403 + c]; v3 = Wih3[(size_t)j * 467 + 403 + c]; }
      else if (c < 464) { v2 = Wih2[(size_t)j * 467 + 3 + c - 64]; v3 = Wih3[(size_t)j * 467 + 3 + c - 64]; }
      else if (c < 467) { v2 = Wih2[(size_t)j * 467 + c - 464]; v3 = Wih3[(size_t)j * 467 + c - 464]; }
      else if (c >= 480 && c < 880) { v2 = Whh2[(size_t)j * 400 + c - 480]; v3 = Whh3[(size_t)j * 400 + c - 480]; }
      W2[c] = (f16)v2;
      W3[c] = (f16)v3;
    }
  } else if (blk < 1728) {
    const int r = blk - 1600;
    f16* WMp = (f16*)(ws + OFF_WM) + (size_t)r * PM;
    for (int c = tid; c < PM; c += 256) {
      const float v = (r < 121 && c < 1200) ? Wm[(size_t)r * 1200 + c] : 0.f;
      WMp[c] = (f16)v;
    }
  } else if (blk == 1728) {
    float* bs1 = (float*)(ws + OFF_BS1);
    float* bs2 = (float*)(ws + OFF_BS2);
    float* bs3 = (float*)(ws + OFF_BS3);
    for (int i = tid; i < 1600; i += 256) {
      bs1[i] = bih1[i] + bhh1[i];
      bs2[i] = bih2[i] + bhh2[i];
      bs3[i] = bih3[i] + bhh3[i];
    }
    float* bwp = (float*)(ws + OFF_BW);
    if (tid < 32) bwp[tid] = (tid < 30) ? bw[tid] : 0.f;
    float* bmp = (float*)(ws + OFF_BM);
    if (tid < 128) bmp[tid] = (tid < 121) ? bm[tid] : 0.f;
  } else if (blk == 1729) {
    unsigned* fl = (unsigned*)(ws + OFF_FLG);
    const int n = 808 * 5 * 16;
    for (int i = tid; i < n; i += 256) {
      const int line = i / 16;
      fl[i] = ((line / 5) < 8) ? 1000u : 0u;  // t<0 presets satisfied
    }
  } else if (blk < 1762) {
    unsigned* az = (unsigned*)(ws + OFF_A1);  // A1,A2,A3,AM contiguous
    const int n = (int)((SZ_A1 + 2 * SZ_A2 + SZ_AM) / 4);
    for (int i = (blk - 1730) * 256 + tid; i < n; i += 32 * 256) az[i] = 0u;
  } else {
    f16* tebp = (f16*)(ws + OFF_TEB);
    const int n = 64 * 96 * 64;
    for (int i = (blk - 1762) * 256 + tid; i < n; i += 128 * 256) {
      const int b = i / (96 * 64);
      const int rem = i % (96 * 64);
      const int u = rem >> 6, d = rem & 63;
      const int tk = tok[b * 96 + u];
      tebp[i] = (f16)emb[(size_t)tk * 64 + d];
    }
  }
}

__global__ void init_x0(char* ws, const float* x) {
  const int tid = (int)threadIdx.x;
  if (tid < 192) {
    const int b = tid / 3, k = tid % 3;
    ((f16*)(ws + OFF_A1))[(size_t)b * P1 + 464 + k] = (f16)x[(size_t)b * Tn * 3 + k];
  }
}

// ---- epilogue: res -> (eos, softmax pi, mu, sigma, rho) ----
__global__ void postproc(const char* ws, float* out) {
  __shared__ float r[50 * 128];
  __shared__ float mx[50], dn[50];
  const float* resb = (const float*)(ws + OFF_RES);
  const int tid = (int)threadIdx.x;
  const int b = (int)blockIdx.x >> 4;
  const int t0 = ((int)blockIdx.x & 15) * 50;
  for (int idx = tid; idx < 50 * 128; idx += 256) {
    const int tt = idx >> 7, c = idx & 127;
    r[idx] = resb[((size_t)(t0 + tt) * 64 + b) * 128 + c];
  }
  __syncthreads();
  if (tid < 50) {
    float m = -1e30f;
    for (int k = 0; k < 20; ++k) m = fmaxf(m, r[tid * 128 + 1 + k]);
    float s = 0.f;
    for (int k = 0; k < 20; ++k) s += expf(r[tid * 128 + 1 + k] - m);
    mx[tid] = m;
    dn[tid] = 1.f / s;
  }
  __syncthreads();
  for (int idx = tid; idx < 50; idx += 256)
    out[O_EOS + (size_t)b * Tn + t0 + idx] = r[idx * 128];
  for (int idx = tid; idx < 50 * 20; idx += 256) {
    const int tt = idx / 20, k = idx % 20;
    const size_t o = ((size_t)b * Tn + t0 + tt) * 20 + k;
    const float* rr = &r[tt * 128];
    out[O_PI + o] = expf(rr[1 + k] - mx[tt]) * dn[tt];
    out[O_MUX + o] = rr[21 + k];
    out[O_MUY + o] = rr[41 + k];
    out[O_SX + o] = expf(rr[61 + k]) + 1e-6f;
    out[O_SY + o] = expf(rr[81 + k]) + 1e-6f;
    out[O_RHO + o] = tanhf(rr[101 + k]) * 0.999f;
  }
}

extern "C" void kernel_launch(void* const* d_in, const int* in_sizes, int n_in,
                              void* d_out, int out_size, void* d_ws, size_t ws_size,
                              hipStream_t stream) {
  const float* x = (const float*)d_in[0];
  const int* tok = (const int*)d_in[1];
  const float* emb = (const float*)d_in[2];
  const float* Wih1 = (const float*)d_in[3];
  const float* Whh1 = (const float*)d_in[4];
  const float* bih1 = (const float*)d_in[5];
  const float* bhh1 = (const float*)d_in[6];
  const float* Wih2 = (const float*)d_in[7];
  const float* Whh2 = (const float*)d_in[8];
  const float* bih2 = (const float*)d_in[9];
  const float* bhh2 = (const float*)d_in[10];
  const float* Wih3 = (const float*)d_in[11];
  const float* Whh3 = (const float*)d_in[12];
  const float* bih3 = (const float*)d_in[13];
  const float* bhh3 = (const float*)d_in[14];
  const float* Ww = (const float*)d_in[15];
  const float* bw = (const float*)d_in[16];
  const float* Wm = (const float*)d_in[17];
  const float* bm = (const float*)d_in[18];
  char* ws = (char*)d_ws;
  float* out = (float*)d_out;

  hipLaunchKernelGGL(init_build, dim3(1890), dim3(256), 0, stream,
                     ws, tok, emb, Wih1, Whh1, bih1, bhh1, Wih2, Whh2, bih2, bhh2,
                     Wih3, Whh3, bih3, bhh3, bw, Wm, bm);
  hipLaunchKernelGGL(init_x0, dim3(1), dim3(256), 0, stream, ws, x);

  hipLaunchKernelGGL(coop_kernel, dim3(NWG), dim3(256), 0, stream, ws, x, Ww);

  hipLaunchKernelGGL(postproc, dim3(1024), dim3(256), 0, stream, ws, out);
}